// Round 1
// baseline (1825.597 us; speedup 1.0000x reference)
//
#include <hip/hip_runtime.h>
#include <math.h>

constexpr int B_ = 128, NA_ = 32, N_ = 4096, E_ = 65536, T_ = 262144;

__device__ __forceinline__ float silu_f(float x){ return x / (1.0f + __expf(-x)); }

// ---------------- CSR build ----------------
__global__ void hist_kernel(const int* __restrict__ idx, int* __restrict__ cnt, int n){
  int i = blockIdx.x*256 + threadIdx.x;
  if(i < n) atomicAdd(&cnt[idx[i]], 1);
}

__global__ void fill_kernel(const int* __restrict__ idx, int* __restrict__ cur, int* __restrict__ list, int n){
  int i = blockIdx.x*256 + threadIdx.x;
  if(i < n){ int p = atomicAdd(&cur[idx[i]], 1); list[p] = i; }
}

template<int PER>
__global__ __launch_bounds__(1024) void scan_kernel(const int* __restrict__ cnt, int* __restrict__ offs,
                                                    int* __restrict__ cur, int n){
  __shared__ int sh[1024];
  int t = threadIdx.x;
  int base = t * PER;
  int s = 0;
  for(int i = 0; i < PER; i++) s += cnt[base + i];
  sh[t] = s;
  __syncthreads();
  for(int d = 1; d < 1024; d <<= 1){
    int v = (t >= d) ? sh[t - d] : 0;
    __syncthreads();
    sh[t] += v;
    __syncthreads();
  }
  int run = sh[t] - s;   // exclusive prefix of this thread's chunk
  for(int i = 0; i < PER; i++){
    offs[base + i] = run; cur[base + i] = run;
    run += cnt[base + i];
  }
  if(t == 1023) offs[n] = run;
}

// ---------------- geometry ----------------
__global__ void pos_kernel(const float* __restrict__ frac, const float* __restrict__ lengths,
                           const float* __restrict__ angles, float* __restrict__ pos){
  int i = blockIdx.x*256 + threadIdx.x;
  if(i >= N_) return;
  int b = i >> 5;  // NA = 32
  const float d2r = 0.017453292519943295f;
  float La = lengths[b*3+0], Lb = lengths[b*3+1], Lc = lengths[b*3+2];
  float al = angles[b*3+0]*d2r, be = angles[b*3+1]*d2r, ga = angles[b*3+2]*d2r;
  float ca = cosf(al), cb = cosf(be), cg = cosf(ga), sg = sinf(ga);
  float cx = cb, cy = (ca - cb*cg) / sg;
  float cz = sqrtf(fmaxf(1.0f - cx*cx - cy*cy, 1e-8f));
  float l00 = La, l10 = Lb*cg, l11 = Lb*sg, l20 = Lc*cx, l21 = Lc*cy, l22 = Lc*cz;
  float fx = frac[i*3], fy = frac[i*3+1], fz = frac[i*3+2];
  pos[i*3+0] = fx*l00 + fy*l10 + fz*l20;
  pos[i*3+1] = fy*l11 + fz*l21;
  pos[i*3+2] = fz*l22;
}

__global__ __launch_bounds__(256) void edge_kernel(const float* __restrict__ pos, const int* __restrict__ ei,
                                                   float* __restrict__ vec, float* __restrict__ rbf){
  int e = blockIdx.x*4 + (threadIdx.x >> 6);
  int lane = threadIdx.x & 63;
  int s = ei[e], d = ei[E_ + e];
  float vx = pos[d*3+0]-pos[s*3+0];
  float vy = pos[d*3+1]-pos[s*3+1];
  float vz = pos[d*3+2]-pos[s*3+2];
  float dd = sqrtf(vx*vx + vy*vy + vz*vz + 1e-12f);
  float dsc = dd * (1.0f/7.0f);
  float env = 0.0f;
  if(dsc < 1.0f){
    float d2 = dsc*dsc, d4 = d2*d2, d5 = d4*dsc;
    env = 1.0f - 21.0f*d5 + 35.0f*d5*dsc - 15.0f*d5*d2;
  }
  float arg = (float)(lane+1) * 3.14159265358979f * dsc;
  rbf[(size_t)e*64 + lane] = env * 0.5345224838248488f * sinf(arg) / dd;
  if(lane < 3){ vec[e*3+lane] = (lane==0) ? vx : (lane==1 ? vy : vz); }
}

__global__ __launch_bounds__(256) void cbf_kernel(const float* __restrict__ vec, const int* __restrict__ ji,
                                                  const int* __restrict__ kj, float* __restrict__ cbf){
  int t = blockIdx.x*16 + (threadIdx.x >> 4);
  int s = threadIdx.x & 15;
  int a = ji[t], b = kj[t];
  float ax = vec[a*3], ay = vec[a*3+1], az = vec[a*3+2];
  float bx = vec[b*3], by = vec[b*3+1], bz = vec[b*3+2];
  float dot = ax*bx + ay*by + az*bz;
  float na = sqrtf(ax*ax + ay*ay + az*az);
  float nb = sqrtf(bx*bx + by*by + bz*bz);
  float cosang = dot / (na*nb + 1e-9f);
  cosang = fminf(fmaxf(cosang, -1.0f + 1e-6f), 1.0f - 1e-6f);
  float ang = acosf(cosang);
  cbf[(size_t)t*16 + s] = cosf((float)s * ang);
}

// ---------------- h init: h = silu([emb[type], noise] @ W_hz) ----------------
__global__ __launch_bounds__(128) void h0_kernel(const float* __restrict__ emb, const int* __restrict__ types,
                                                 const float* __restrict__ noise, const float* __restrict__ Whz,
                                                 float* __restrict__ h){
  __shared__ float arow[129];
  int i = blockIdx.x;
  int c = threadIdx.x;
  arow[c] = emb[(size_t)types[i]*128 + c];
  if(c == 0) arow[128] = noise[i >> 5];
  __syncthreads();
  float acc = 0.f;
  for(int k = 0; k < 129; k++) acc += arow[k] * Whz[(size_t)k*128 + c];
  h[(size_t)i*128 + c] = silu_f(acc);
}

// ---------------- m init GEMM: m = silu(concat(h[src],h[dst],rbf) @ W_edge) ----------------
__global__ __launch_bounds__(256) void gemm_m0(const float* __restrict__ h, const float* __restrict__ rbf,
                                               const int* __restrict__ ei, const float* __restrict__ W,
                                               float* __restrict__ mout){
  constexpr int LDA = 68;
  __shared__ float sA[32*LDA];
  __shared__ float sW[32*128];
  int tid = threadIdx.x;
  int tx = tid & 31, ty = tid >> 5;
  int row0 = blockIdx.x * 64;
  float acc[8][4];
  #pragma unroll
  for(int r=0;r<8;r++){ acc[r][0]=0.f; acc[r][1]=0.f; acc[r][2]=0.f; acc[r][3]=0.f; }
  for(int k0 = 0; k0 < 320; k0 += 32){
    #pragma unroll
    for(int i=0;i<8;i++){
      int idx = i*256 + tid;
      int r = idx >> 5, k = idx & 31;
      int e = row0 + r, kg = k0 + k;
      float v;
      if(kg < 128)      v = h[(size_t)ei[e]*128 + kg];
      else if(kg < 256) v = h[(size_t)ei[E_+e]*128 + (kg-128)];
      else              v = rbf[(size_t)e*64 + (kg-256)];
      sA[k*LDA + r] = v;
    }
    #pragma unroll
    for(int i=0;i<16;i++){
      int idx = i*256 + tid;
      int k = idx >> 7, c = idx & 127;
      sW[idx] = W[(size_t)(k0+k)*128 + c];
    }
    __syncthreads();
    #pragma unroll
    for(int kk=0;kk<32;kk++){
      float4 wv = *(const float4*)&sW[kk*128 + tx*4];
      #pragma unroll
      for(int r4=0;r4<2;r4++){
        float4 av = *(const float4*)&sA[kk*LDA + ty*8 + r4*4];
        float aa[4] = {av.x, av.y, av.z, av.w};
        #pragma unroll
        for(int rr=0;rr<4;rr++){
          int r = r4*4 + rr;
          acc[r][0] += aa[rr]*wv.x; acc[r][1] += aa[rr]*wv.y;
          acc[r][2] += aa[rr]*wv.z; acc[r][3] += aa[rr]*wv.w;
        }
      }
    }
    __syncthreads();
  }
  #pragma unroll
  for(int r=0;r<8;r++){
    size_t off = (size_t)(row0 + ty*8 + r)*128 + tx*4;
    float4 v;
    v.x = silu_f(acc[r][0]); v.y = silu_f(acc[r][1]);
    v.z = silu_f(acc[r][2]); v.w = silu_f(acc[r][3]);
    *(float4*)&mout[off] = v;
  }
}

// ---------------- generic tiled GEMM ----------------
// EPI: 0=store (or DUAL product), 1=silu, 2=C+=silu, 3=relu(x+bias), 4=x+bias
template<int BM,int BN,int EPI,bool DUAL,bool CGUARD>
__global__ __launch_bounds__(256) void gemm_k(
    const float* __restrict__ A, const float* __restrict__ W, int K,
    const float* __restrict__ A2, const float* __restrict__ W2, int K2,
    float* __restrict__ C, int ncols, const float* __restrict__ bias)
{
  constexpr int CGN = BN/4;
  constexpr int TG  = 256/CGN;
  constexpr int RT  = BM/TG;
  constexpr int LDA = BM + 4;
  __shared__ float sA[32*LDA];
  __shared__ float sW[32*BN];
  const int tid = threadIdx.x;
  const int tx = tid % CGN, ty = tid / CGN;
  const int row0 = blockIdx.x * BM;
  const int col0 = blockIdx.y * BN;
  float acc[RT][4];
  float sv[RT][4];
  #pragma unroll
  for(int r=0;r<RT;r++){ acc[r][0]=0.f; acc[r][1]=0.f; acc[r][2]=0.f; acc[r][3]=0.f; }

  const float* Ap = A; const float* Wp = W; int Kv = K;
  const int npass = DUAL ? 2 : 1;
  for(int pass = 0; pass < npass; ++pass){
    if(pass == 1){
      #pragma unroll
      for(int r=0;r<RT;r++)
        #pragma unroll
        for(int j=0;j<4;j++){ sv[r][j] = silu_f(acc[r][j]); acc[r][j] = 0.f; }
      Ap = A2; Wp = W2; Kv = K2;
    }
    for(int k0 = 0; k0 < Kv; k0 += 32){
      #pragma unroll
      for(int i=0;i<(BM*32)/256;i++){
        int idx = i*256 + tid; int r = idx >> 5, k = idx & 31;
        sA[k*LDA + r] = Ap[(size_t)(row0+r)*Kv + (k0+k)];
      }
      #pragma unroll
      for(int i=0;i<(32*BN)/256;i++){
        int idx = i*256 + tid; int k = idx / BN, c = idx % BN;
        float w = 0.f;
        if(!CGUARD || (col0 + c) < ncols) w = Wp[(size_t)(k0+k)*ncols + col0 + c];
        sW[idx] = w;
      }
      __syncthreads();
      #pragma unroll
      for(int kk=0;kk<32;kk++){
        float4 wv = *(const float4*)&sW[kk*BN + tx*4];
        #pragma unroll
        for(int r4=0;r4<RT/4;r4++){
          float4 av = *(const float4*)&sA[kk*LDA + ty*RT + r4*4];
          float aa[4] = {av.x, av.y, av.z, av.w};
          #pragma unroll
          for(int rr=0;rr<4;rr++){
            int r = r4*4 + rr;
            acc[r][0] += aa[rr]*wv.x; acc[r][1] += aa[rr]*wv.y;
            acc[r][2] += aa[rr]*wv.z; acc[r][3] += aa[rr]*wv.w;
          }
        }
      }
      __syncthreads();
    }
  }

  #pragma unroll
  for(int r=0;r<RT;r++){
    size_t off = (size_t)(row0 + ty*RT + r)*ncols + col0 + tx*4;
    #pragma unroll
    for(int j=0;j<4;j++){
      int cc = col0 + tx*4 + j;
      bool ok = (!CGUARD) || (cc < ncols);
      float x = DUAL ? sv[r][j]*acc[r][j] : acc[r][j];
      if(EPI == 1) x = silu_f(x);
      else if(EPI == 2) x = (ok ? C[off+j] : 0.f) + silu_f(x);
      else if(EPI == 3) x = fmaxf(x + (ok ? bias[cc] : 0.f), 0.f);
      else if(EPI == 4) x = x + (ok ? bias[cc] : 0.f);
      if(ok) C[off+j] = x;
    }
  }
}

// ---------------- triplet segment-sum: ts[e] = sum_{t: ji[t]=e} x[kj[t]] * (cbf[t] @ Wcbf) ----------------
__global__ __launch_bounds__(256) void tsum_kernel(const int* __restrict__ offs, const int* __restrict__ list,
                                                   const int* __restrict__ kj, const float* __restrict__ cbf,
                                                   const float* __restrict__ x, const float* __restrict__ Wc,
                                                   float* __restrict__ ts){
  int e = blockIdx.x*4 + (threadIdx.x >> 6);
  int lane = threadIdx.x & 63;
  float wc[16];
  #pragma unroll
  for(int s=0;s<16;s++) wc[s] = Wc[s*64 + lane];
  float acc = 0.f;
  int b0 = offs[e], b1 = offs[e+1];
  for(int idx = b0; idx < b1; ++idx){
    int t = list[idx];
    int k = kj[t];
    const float* cb = &cbf[(size_t)t*16];
    float cw = 0.f;
    #pragma unroll
    for(int s=0;s<16;s++) cw += cb[s]*wc[s];
    acc += x[(size_t)k*64 + lane] * cw;
  }
  ts[(size_t)e*64 + lane] = acc;
}

// ---------------- edge->atom segment-sum over dst ----------------
__global__ __launch_bounds__(128) void asum_kernel(const int* __restrict__ offs, const int* __restrict__ list,
                                                   const float* __restrict__ buf, float* __restrict__ a){
  int i = blockIdx.x;
  int c = threadIdx.x;
  float acc = 0.f;
  int b0 = offs[i], b1 = offs[i+1];
  for(int idx = b0; idx < b1; ++idx){
    acc += buf[(size_t)list[idx]*128 + c];
  }
  a[(size_t)i*128 + c] = acc;
}

// ---------------- m[e] += silu(hs[src[e]] + ht[dst[e]]) ----------------
__global__ __launch_bounds__(256) void scat_kernel(const int* __restrict__ ei, const float* __restrict__ hs,
                                                   const float* __restrict__ ht, float* __restrict__ m){
  int e = blockIdx.x*2 + (threadIdx.x >> 7);
  int c = threadIdx.x & 127;
  int s = ei[e], d = ei[E_ + e];
  float v = hs[(size_t)s*128 + c] + ht[(size_t)d*128 + c];
  m[(size_t)e*128 + c] += silu_f(v);
}

// ---------------- z[b] = mean over atoms of hW ----------------
__global__ __launch_bounds__(128) void zred_kernel(const float* __restrict__ hW, const int* __restrict__ numat,
                                                   float* __restrict__ z){
  int b = blockIdx.x, c = threadIdx.x;
  float s = 0.f;
  for(int i=0;i<32;i++) s += hW[((size_t)b*32 + i)*128 + c];
  z[(size_t)b*128 + c] = s / (float)numat[b];
}

extern "C" void kernel_launch(void* const* d_in, const int* in_sizes, int n_in,
                              void* d_out, int out_size, void* d_ws, size_t ws_size,
                              hipStream_t stream)
{
  const float* noise   = (const float*)d_in[0];
  const float* frac    = (const float*)d_in[1];
  const float* lengths = (const float*)d_in[2];
  const float* angles  = (const float*)d_in[3];
  const int*   types   = (const int*)d_in[4];
  const int*   numat   = (const int*)d_in[5];
  const int*   ei      = (const int*)d_in[6];
  const int*   ji      = (const int*)d_in[7];
  const int*   kj      = (const int*)d_in[8];
  const float* emb     = (const float*)d_in[9];
  const float* Whz     = (const float*)d_in[10];
  const float* Wedge   = (const float*)d_in[11];
  const float* Wm      = (const float*)d_in[12];
  const float* Wr1     = (const float*)d_in[13];
  const float* Wdown   = (const float*)d_in[14];
  const float* Wcbf    = (const float*)d_in[15];
  const float* Wup     = (const float*)d_in[16];
  const float* Wa      = (const float*)d_in[17];
  const float* Wr2     = (const float*)d_in[18];
  const float* Wh      = (const float*)d_in[19];
  const float* Wsw     = (const float*)d_in[20];
  const float* Wtw     = (const float*)d_in[21];
  const float* Wout    = (const float*)d_in[22];
  const float* Wfc0    = (const float*)d_in[23];
  const float* bfc0    = (const float*)d_in[24];
  const float* Wfc1    = (const float*)d_in[25];
  const float* bfc1    = (const float*)d_in[26];
  const float* Wfc2    = (const float*)d_in[27];
  const float* bfc2    = (const float*)d_in[28];
  float* out = (float*)d_out;

  float* wsf = (float*)d_ws;
  size_t o = 0;
  auto alloc = [&](size_t n){ float* p = wsf + o; o += n; return p; };
  float* pos    = alloc((size_t)N_*3);
  float* rbf    = alloc((size_t)E_*64);
  float* cbf    = alloc((size_t)T_*16);
  float* h      = alloc((size_t)N_*128);
  float* m      = alloc((size_t)E_*128);
  float* buf128 = alloc((size_t)E_*128);   // aliased: vec (pre-loop), tmp, ts, aWa*r2
  float* bufx   = alloc((size_t)E_*64);
  float* a      = alloc((size_t)N_*128);
  float* hsb    = alloc((size_t)N_*128);   // hs / hW
  float* htb    = alloc((size_t)N_*128);
  float* z      = alloc(128*128);
  float* f0     = alloc(128*256);
  float* f1     = alloc(128*256);
  int* ib = (int*)(wsf + o);
  int* cnt_ji   = ib; ib += E_;
  int* off_ji   = ib; ib += E_ + 1;
  int* cur_ji   = ib; ib += E_;
  int* list_ji  = ib; ib += T_;
  int* cnt_dst  = ib; ib += N_;
  int* off_dst  = ib; ib += N_ + 1;
  int* cur_dst  = ib; ib += N_;
  int* list_dst = ib; ib += E_;

  float* vec = buf128;
  float* ts  = buf128;

  // CSR builds (inputs are fixed, but rebuilt every call — no static state)
  hipMemsetAsync(cnt_ji, 0, E_*sizeof(int), stream);
  hipMemsetAsync(cnt_dst, 0, N_*sizeof(int), stream);
  hist_kernel<<<T_/256, 256, 0, stream>>>(ji, cnt_ji, T_);
  hist_kernel<<<E_/256, 256, 0, stream>>>(ei + E_, cnt_dst, E_);
  scan_kernel<64><<<1, 1024, 0, stream>>>(cnt_ji, off_ji, cur_ji, E_);
  scan_kernel<4><<<1, 1024, 0, stream>>>(cnt_dst, off_dst, cur_dst, N_);
  fill_kernel<<<T_/256, 256, 0, stream>>>(ji, cur_ji, list_ji, T_);
  fill_kernel<<<E_/256, 256, 0, stream>>>(ei + E_, cur_dst, list_dst, E_);

  // geometry + embeddings
  pos_kernel<<<N_/256, 256, 0, stream>>>(frac, lengths, angles, pos);
  edge_kernel<<<E_/4, 256, 0, stream>>>(pos, ei, vec, rbf);
  cbf_kernel<<<T_/16, 256, 0, stream>>>(vec, ji, kj, cbf);
  h0_kernel<<<N_, 128, 0, stream>>>(emb, types, noise, Whz, h);
  gemm_m0<<<E_/64, 256, 0, stream>>>(h, rbf, ei, Wedge, m);

  for(int b = 0; b < 3; b++){
    const float* Wm_b  = Wm   + (size_t)b*128*128;
    const float* Wr1_b = Wr1  + (size_t)b*64*128;
    const float* Wd_b  = Wdown+ (size_t)b*128*64;
    const float* Wc_b  = Wcbf + (size_t)b*16*64;
    const float* Wu_b  = Wup  + (size_t)b*64*128;
    const float* Wa_b  = Wa   + (size_t)b*128*128;
    const float* Wr2_b = Wr2  + (size_t)b*64*128;
    const float* Wh_b  = Wh   + (size_t)b*128*128;
    const float* Ws_b  = Wsw  + (size_t)b*128*128;
    const float* Wt_b  = Wtw  + (size_t)b*128*128;

    // tmp = silu(m @ Wm) * (rbf @ Wr1)
    gemm_k<64,128,0,true,false><<<dim3(E_/64,1), 256, 0, stream>>>(m, Wm_b, 128, rbf, Wr1_b, 64, buf128, 128, nullptr);
    // x = tmp @ Wdown   [E,64]
    gemm_k<128,64,0,false,false><<<dim3(E_/128,1), 256, 0, stream>>>(buf128, Wd_b, 128, nullptr, nullptr, 0, bufx, 64, nullptr);
    // ts = seg(x[kj]*(cbf@Wcbf), ji)   (overwrites buf128 — tmp already consumed)
    tsum_kernel<<<E_/4, 256, 0, stream>>>(off_ji, list_ji, kj, cbf, bufx, Wc_b, ts);
    // m += silu(ts @ Wup)
    gemm_k<64,128,2,false,false><<<dim3(E_/64,1), 256, 0, stream>>>(ts, Wu_b, 64, nullptr, nullptr, 0, m, 128, nullptr);
    // buf128 = silu(m @ Wa) * (rbf @ Wr2)
    gemm_k<64,128,0,true,false><<<dim3(E_/64,1), 256, 0, stream>>>(m, Wa_b, 128, rbf, Wr2_b, 64, buf128, 128, nullptr);
    // a = seg(buf128, dst)
    asum_kernel<<<N_, 128, 0, stream>>>(off_dst, list_dst, buf128, a);
    // h += silu(a @ Wh)
    gemm_k<32,128,2,false,false><<<dim3(N_/32,1), 256, 0, stream>>>(a, Wh_b, 128, nullptr, nullptr, 0, h, 128, nullptr);
    // hs = h @ Ws ; ht = h @ Wt
    gemm_k<32,128,0,false,false><<<dim3(N_/32,1), 256, 0, stream>>>(h, Ws_b, 128, nullptr, nullptr, 0, hsb, 128, nullptr);
    gemm_k<32,128,0,false,false><<<dim3(N_/32,1), 256, 0, stream>>>(h, Wt_b, 128, nullptr, nullptr, 0, htb, 128, nullptr);
    // m += silu(hs[src] + ht[dst])
    scat_kernel<<<E_/2, 256, 0, stream>>>(ei, hsb, htb, m);
  }

  // readout
  gemm_k<32,128,0,false,false><<<dim3(N_/32,1), 256, 0, stream>>>(h, Wout, 128, nullptr, nullptr, 0, hsb, 128, nullptr);
  zred_kernel<<<128, 128, 0, stream>>>(hsb, numat, z);
  gemm_k<32,128,3,false,false><<<dim3(4,2), 256, 0, stream>>>(z,  Wfc0, 128, nullptr, nullptr, 0, f0, 256, bfc0);
  gemm_k<32,128,3,false,false><<<dim3(4,2), 256, 0, stream>>>(f0, Wfc1, 256, nullptr, nullptr, 0, f1, 256, bfc1);
  gemm_k<32,128,4,false,true ><<<dim3(4,2), 256, 0, stream>>>(f1, Wfc2, 256, nullptr, nullptr, 0, out, 230, bfc2);
}

// Round 2
// 881.183 us; speedup vs baseline: 2.0718x; 2.0718x over previous
//
#include <hip/hip_runtime.h>
#include <hip/hip_bf16.h>
#include <math.h>

constexpr int B_ = 128, N_ = 4096, E_ = 65536, T_ = 262144;

typedef __attribute__((ext_vector_type(8))) __bf16 bf16x8;
typedef __attribute__((ext_vector_type(4))) float f32x4;
typedef __hip_bfloat16 bf16;

__device__ __forceinline__ float silu_f(float x){ return x / (1.0f + __expf(-x)); }
__device__ __forceinline__ float bf2f(bf16 v){ return __bfloat162float(v); }
__device__ __forceinline__ bf16  f2bf(float v){ return __float2bfloat16(v); }

// ================= CSR build =================
__global__ void hist_kernel(const int* __restrict__ idx, int* __restrict__ cnt, int n){
  int i = blockIdx.x*256 + threadIdx.x;
  if(i < n) atomicAdd(&cnt[idx[i]], 1);
}
__global__ void fill_kernel(const int* __restrict__ idx, int* __restrict__ cur, int* __restrict__ list, int n){
  int i = blockIdx.x*256 + threadIdx.x;
  if(i < n){ int p = atomicAdd(&cur[idx[i]], 1); list[p] = i; }
}
template<int PER>
__global__ __launch_bounds__(1024) void scan_kernel(const int* __restrict__ cnt, int* __restrict__ offs,
                                                    int* __restrict__ cur, int n){
  __shared__ int sh[1024];
  int t = threadIdx.x;
  int base = t * PER;
  int s = 0;
  for(int i = 0; i < PER; i++) s += cnt[base + i];
  sh[t] = s;
  __syncthreads();
  for(int d = 1; d < 1024; d <<= 1){
    int v = (t >= d) ? sh[t - d] : 0;
    __syncthreads();
    sh[t] += v;
    __syncthreads();
  }
  int run = sh[t] - s;
  for(int i = 0; i < PER; i++){
    offs[base + i] = run; cur[base + i] = run;
    run += cnt[base + i];
  }
  if(t == 1023) offs[n] = run;
}

// ================= geometry =================
__global__ void pos_kernel(const float* __restrict__ frac, const float* __restrict__ lengths,
                           const float* __restrict__ angles, float* __restrict__ pos){
  int i = blockIdx.x*256 + threadIdx.x;
  if(i >= N_) return;
  int b = i >> 5;
  const float d2r = 0.017453292519943295f;
  float La = lengths[b*3+0], Lb = lengths[b*3+1], Lc = lengths[b*3+2];
  float al = angles[b*3+0]*d2r, be = angles[b*3+1]*d2r, ga = angles[b*3+2]*d2r;
  float ca = cosf(al), cb = cosf(be), cg = cosf(ga), sg = sinf(ga);
  float cx = cb, cy = (ca - cb*cg) / sg;
  float cz = sqrtf(fmaxf(1.0f - cx*cx - cy*cy, 1e-8f));
  float l00 = La, l10 = Lb*cg, l11 = Lb*sg, l20 = Lc*cx, l21 = Lc*cy, l22 = Lc*cz;
  float fx = frac[i*3], fy = frac[i*3+1], fz = frac[i*3+2];
  pos[i*3+0] = fx*l00 + fy*l10 + fz*l20;
  pos[i*3+1] = fy*l11 + fz*l21;
  pos[i*3+2] = fz*l22;
}

__global__ __launch_bounds__(256) void edge_kernel(const float* __restrict__ pos, const int* __restrict__ ei,
                                                   float* __restrict__ vec, bf16* __restrict__ rbf){
  int e = blockIdx.x*4 + (threadIdx.x >> 6);
  int lane = threadIdx.x & 63;
  int s = ei[e], d = ei[E_ + e];
  float vx = pos[d*3+0]-pos[s*3+0];
  float vy = pos[d*3+1]-pos[s*3+1];
  float vz = pos[d*3+2]-pos[s*3+2];
  float dd = sqrtf(vx*vx + vy*vy + vz*vz + 1e-12f);
  float dsc = dd * (1.0f/7.0f);
  float env = 0.0f;
  if(dsc < 1.0f){
    float d2 = dsc*dsc, d5 = d2*d2*dsc;
    env = 1.0f - 21.0f*d5 + 35.0f*d5*dsc - 15.0f*d5*d2;
  }
  float arg = (float)(lane+1) * 3.14159265358979f * dsc;
  rbf[(size_t)e*64 + lane] = f2bf(env * 0.5345224838248488f * sinf(arg) / dd);
  if(lane < 3){ vec[e*3+lane] = (lane==0) ? vx : (lane==1 ? vy : vz); }
}

__global__ __launch_bounds__(256) void cbf_kernel(const float* __restrict__ vec, const int* __restrict__ ji,
                                                  const int* __restrict__ kj, float* __restrict__ cbf){
  int t = blockIdx.x*16 + (threadIdx.x >> 4);
  int s = threadIdx.x & 15;
  int a = ji[t], b = kj[t];
  float ax = vec[a*3], ay = vec[a*3+1], az = vec[a*3+2];
  float bx = vec[b*3], by = vec[b*3+1], bz = vec[b*3+2];
  float dot = ax*bx + ay*by + az*bz;
  float na = sqrtf(ax*ax + ay*ay + az*az);
  float nb = sqrtf(bx*bx + by*by + bz*bz);
  float cosang = dot / (na*nb + 1e-9f);
  cosang = fminf(fmaxf(cosang, -1.0f + 1e-6f), 1.0f - 1e-6f);
  float ang = acosf(cosang);
  cbf[(size_t)t*16 + s] = cosf((float)s * ang);
}

// ================= weight transpose+convert: fp32 [K,N] -> bf16 [N][K] =================
struct WDesc { const float* src; bf16* dst; int K; int shN; };
struct WPack { WDesc d[16]; };
__global__ __launch_bounds__(256) void wconv_kernel(WPack p){
  WDesc w = p.d[blockIdx.y];
  int idx = blockIdx.x*256 + threadIdx.x;
  int NN = 1 << w.shN;
  if(idx >= w.K * NN) return;
  int k = idx >> w.shN, c = idx & (NN - 1);
  w.dst[(size_t)c * w.K + k] = f2bf(w.src[idx]);
}

// ================= h init =================
__global__ __launch_bounds__(128) void h0_kernel(const float* __restrict__ emb, const int* __restrict__ types,
                                                 const float* __restrict__ noise, const float* __restrict__ Whz,
                                                 float* __restrict__ h, bf16* __restrict__ hbf){
  __shared__ float arow[129];
  int i = blockIdx.x;
  int c = threadIdx.x;
  arow[c] = emb[(size_t)types[i]*128 + c];
  if(c == 0) arow[128] = noise[i >> 5];
  __syncthreads();
  float acc = 0.f;
  for(int k = 0; k < 129; k++) acc += arow[k] * Whz[(size_t)k*128 + c];
  float v = silu_f(acc);
  h[(size_t)i*128 + c] = v;
  hbf[(size_t)i*128 + c] = f2bf(v);
}

// ================= MFMA GEMM (LDS-free) =================
// A: bf16 [M,K] row-major. W: bf16 [N][K] (pre-transposed). Block = 128 rows x N cols, 4 waves.
// A-frag: lane l -> row (l&15), k = 8*(l>>4)+j.  B-frag symmetric.  D: col=l&15, row=(l>>4)*4+reg.
template<int KK, int FM>
__device__ __forceinline__ void kloop(const bf16* __restrict__ A, const bf16* __restrict__ W,
                                      int rowA0, int colW0, int lr, int lk, f32x4 (*acc)[4])
{
  #pragma unroll
  for(int k0 = 0; k0 < KK; k0 += 32){
    bf16x8 af[FM], bv[4];
    #pragma unroll
    for(int fm = 0; fm < FM; fm++)
      af[fm] = *(const bf16x8*)(A + (size_t)(rowA0 + fm*16 + lr)*KK + k0 + lk*8);
    #pragma unroll
    for(int fn = 0; fn < 4; fn++)
      bv[fn] = *(const bf16x8*)(W + (size_t)(colW0 + fn*16 + lr)*KK + k0 + lk*8);
    #pragma unroll
    for(int fm = 0; fm < FM; fm++)
      #pragma unroll
      for(int fn = 0; fn < 4; fn++)
        acc[fm][fn] = __builtin_amdgcn_mfma_f32_16x16x32_bf16(af[fm], bv[fn], acc[fm][fn], 0, 0, 0);
  }
}

// EPI: 0=store, 2=bf16 C += silu(x), 3=fp32 Res += silu(x) and bf16 mirror store
template<int K1, int N, int EPI, bool DUAL, int K2, bool OUTF32>
__global__ __launch_bounds__(256, 2) void mgemm(
    const bf16* __restrict__ A, const bf16* __restrict__ W,
    const bf16* __restrict__ A2, const bf16* __restrict__ W2,
    void* __restrict__ Cout, float* __restrict__ Res)
{
  constexpr int WC = N/64, WR = 4/WC, RPW = 128/WR, FM = RPW/16;
  const int tid = threadIdx.x;
  const int wid = tid >> 6, lane = tid & 63;
  const int wr = wid / WC, wc = wid % WC;
  const int lr = lane & 15, lk = lane >> 4;
  const int rowA0 = blockIdx.x*128 + wr*RPW;
  const int colW0 = wc*64;

  f32x4 acc[FM][4];
  #pragma unroll
  for(int i = 0; i < FM; i++)
    #pragma unroll
    for(int j = 0; j < 4; j++) acc[i][j] = (f32x4){0.f,0.f,0.f,0.f};

  kloop<K1, FM>(A, W, rowA0, colW0, lr, lk, acc);

  float sv[FM][4][4];
  if constexpr (DUAL){
    #pragma unroll
    for(int i = 0; i < FM; i++)
      #pragma unroll
      for(int j = 0; j < 4; j++){
        #pragma unroll
        for(int r = 0; r < 4; r++) sv[i][j][r] = silu_f(acc[i][j][r]);
        acc[i][j] = (f32x4){0.f,0.f,0.f,0.f};
      }
    kloop<(DUAL ? K2 : 32), FM>(A2, W2, rowA0, colW0, lr, lk, acc);
  }

  #pragma unroll
  for(int fm = 0; fm < FM; fm++){
    #pragma unroll
    for(int fn = 0; fn < 4; fn++){
      #pragma unroll
      for(int r = 0; r < 4; r++){
        int row = rowA0 + fm*16 + lk*4 + r;
        int col = colW0 + fn*16 + lr;
        size_t off = (size_t)row * N + col;
        float x = acc[fm][fn][r];
        if constexpr (DUAL) x = sv[fm][fn][r] * x;
        if constexpr (EPI == 2){
          bf16* C = (bf16*)Cout;
          x = bf2f(C[off]) + silu_f(x);
          C[off] = f2bf(x);
        } else if constexpr (EPI == 3){
          x = Res[off] + silu_f(x);
          Res[off] = x;
          ((bf16*)Cout)[off] = f2bf(x);
        } else {
          if constexpr (OUTF32) ((float*)Cout)[off] = x;
          else ((bf16*)Cout)[off] = f2bf(x);
        }
      }
    }
  }
}

// m0: A = concat(h[src], h[dst], rbf) gathered, K=320, N=128, epilogue silu -> bf16
__global__ __launch_bounds__(256, 2) void mgemm_m0(
    const bf16* __restrict__ hb, const bf16* __restrict__ rbf, const int* __restrict__ ei,
    const bf16* __restrict__ Wt /*[128][320]*/, bf16* __restrict__ mout)
{
  const int tid = threadIdx.x;
  const int wid = tid >> 6, lane = tid & 63;
  const int wr = wid >> 1, wc = wid & 1;
  const int lr = lane & 15, lk = lane >> 4;
  const int e0 = blockIdx.x*128 + wr*64;

  int esrc[4], edst[4];
  #pragma unroll
  for(int fm = 0; fm < 4; fm++){
    int e = e0 + fm*16 + lr;
    esrc[fm] = ei[e]; edst[fm] = ei[E_ + e];
  }

  f32x4 acc[4][4];
  #pragma unroll
  for(int i = 0; i < 4; i++)
    #pragma unroll
    for(int j = 0; j < 4; j++) acc[i][j] = (f32x4){0.f,0.f,0.f,0.f};

  #pragma unroll
  for(int ks = 0; ks < 10; ks++){
    const int k0 = ks*32;
    bf16x8 af[4], bv[4];
    #pragma unroll
    for(int fm = 0; fm < 4; fm++){
      const bf16* p;
      if(k0 < 128)      p = hb + (size_t)esrc[fm]*128 + k0;
      else if(k0 < 256) p = hb + (size_t)edst[fm]*128 + (k0 - 128);
      else              p = rbf + (size_t)(e0 + fm*16 + lr)*64 + (k0 - 256);
      af[fm] = *(const bf16x8*)(p + lk*8);
    }
    #pragma unroll
    for(int fn = 0; fn < 4; fn++)
      bv[fn] = *(const bf16x8*)(Wt + (size_t)(wc*64 + fn*16 + lr)*320 + k0 + lk*8);
    #pragma unroll
    for(int fm = 0; fm < 4; fm++)
      #pragma unroll
      for(int fn = 0; fn < 4; fn++)
        acc[fm][fn] = __builtin_amdgcn_mfma_f32_16x16x32_bf16(af[fm], bv[fn], acc[fm][fn], 0, 0, 0);
  }

  #pragma unroll
  for(int fm = 0; fm < 4; fm++)
    #pragma unroll
    for(int fn = 0; fn < 4; fn++)
      #pragma unroll
      for(int r = 0; r < 4; r++){
        int row = e0 + fm*16 + lk*4 + r;
        int col = wc*64 + fn*16 + lr;
        mout[(size_t)row*128 + col] = f2bf(silu_f(acc[fm][fn][r]));
      }
}

// ================= triplet segsum =================
__global__ __launch_bounds__(256) void tsum_kernel(const int* __restrict__ offs, const int* __restrict__ list,
                                                   const int* __restrict__ kj, const float* __restrict__ cbf,
                                                   const bf16* __restrict__ x, const float* __restrict__ Wc,
                                                   bf16* __restrict__ ts){
  int e = blockIdx.x*4 + (threadIdx.x >> 6);
  int lane = threadIdx.x & 63;
  float wc[16];
  #pragma unroll
  for(int s = 0; s < 16; s++) wc[s] = Wc[s*64 + lane];
  float acc = 0.f;
  int b0 = offs[e], b1 = offs[e+1];
  for(int idx = b0; idx < b1; ++idx){
    int t = list[idx];
    int k = kj[t];
    const float* cb = &cbf[(size_t)t*16];
    float cw = 0.f;
    #pragma unroll
    for(int s = 0; s < 16; s++) cw += cb[s]*wc[s];
    acc += bf2f(x[(size_t)k*64 + lane]) * cw;
  }
  ts[(size_t)e*64 + lane] = f2bf(acc);
}

// ================= edge->atom segsum =================
__global__ __launch_bounds__(128) void asum_kernel(const int* __restrict__ offs, const int* __restrict__ list,
                                                   const bf16* __restrict__ buf, bf16* __restrict__ a){
  int i = blockIdx.x;
  int c = threadIdx.x;
  float acc = 0.f;
  int b0 = offs[i], b1 = offs[i+1];
  for(int idx = b0; idx < b1; ++idx)
    acc += bf2f(buf[(size_t)list[idx]*128 + c]);
  a[(size_t)i*128 + c] = f2bf(acc);
}

// ================= m[e] += silu(hs[src]+ht[dst]) =================
__global__ __launch_bounds__(256) void scat_kernel(const int* __restrict__ ei, const float* __restrict__ hs,
                                                   const float* __restrict__ ht, bf16* __restrict__ m){
  int e = blockIdx.x*2 + (threadIdx.x >> 7);
  int c = threadIdx.x & 127;
  int s = ei[e], d = ei[E_ + e];
  float v = hs[(size_t)s*128 + c] + ht[(size_t)d*128 + c];
  size_t off = (size_t)e*128 + c;
  m[off] = f2bf(bf2f(m[off]) + silu_f(v));
}

// ================= z mean =================
__global__ __launch_bounds__(128) void zred_kernel(const float* __restrict__ hW, const int* __restrict__ numat,
                                                   float* __restrict__ z){
  int b = blockIdx.x, c = threadIdx.x;
  float s = 0.f;
  for(int i = 0; i < 32; i++) s += hW[((size_t)b*32 + i)*128 + c];
  z[(size_t)b*128 + c] = s / (float)numat[b];
}

// ================= fp32 tiled GEMM (final MLP only) =================
template<int BM,int BN,int EPI,bool CGUARD>
__global__ __launch_bounds__(256) void gemm_k(
    const float* __restrict__ A, const float* __restrict__ W, int K,
    float* __restrict__ C, int ncols, const float* __restrict__ bias)
{
  constexpr int CGN = BN/4;
  constexpr int TG  = 256/CGN;
  constexpr int RT  = BM/TG;
  constexpr int LDA = BM + 4;
  __shared__ float sA[32*LDA];
  __shared__ float sW[32*BN];
  const int tid = threadIdx.x;
  const int tx = tid % CGN, ty = tid / CGN;
  const int row0 = blockIdx.x * BM;
  const int col0 = blockIdx.y * BN;
  float acc[RT][4];
  #pragma unroll
  for(int r=0;r<RT;r++){ acc[r][0]=0.f; acc[r][1]=0.f; acc[r][2]=0.f; acc[r][3]=0.f; }

  for(int k0 = 0; k0 < K; k0 += 32){
    #pragma unroll
    for(int i=0;i<(BM*32)/256;i++){
      int idx = i*256 + tid; int r = idx >> 5, k = idx & 31;
      sA[k*LDA + r] = A[(size_t)(row0+r)*K + (k0+k)];
    }
    #pragma unroll
    for(int i=0;i<(32*BN)/256;i++){
      int idx = i*256 + tid; int k = idx / BN, c = idx % BN;
      float w = 0.f;
      if(!CGUARD || (col0 + c) < ncols) w = W[(size_t)(k0+k)*ncols + col0 + c];
      sW[idx] = w;
    }
    __syncthreads();
    #pragma unroll
    for(int kk=0;kk<32;kk++){
      float4 wv = *(const float4*)&sW[kk*BN + tx*4];
      #pragma unroll
      for(int r4=0;r4<RT/4;r4++){
        float4 av = *(const float4*)&sA[kk*LDA + ty*RT + r4*4];
        float aa[4] = {av.x, av.y, av.z, av.w};
        #pragma unroll
        for(int rr=0;rr<4;rr++){
          int r = r4*4 + rr;
          acc[r][0] += aa[rr]*wv.x; acc[r][1] += aa[rr]*wv.y;
          acc[r][2] += aa[rr]*wv.z; acc[r][3] += aa[rr]*wv.w;
        }
      }
    }
    __syncthreads();
  }

  #pragma unroll
  for(int r=0;r<RT;r++){
    size_t off = (size_t)(row0 + ty*RT + r)*ncols + col0 + tx*4;
    #pragma unroll
    for(int j=0;j<4;j++){
      int cc = col0 + tx*4 + j;
      bool ok = (!CGUARD) || (cc < ncols);
      float x = acc[r][j];
      if(EPI == 3) x = fmaxf(x + (ok ? bias[cc] : 0.f), 0.f);
      else if(EPI == 4) x = x + (ok ? bias[cc] : 0.f);
      if(ok) C[off+j] = x;
    }
  }
}

extern "C" void kernel_launch(void* const* d_in, const int* in_sizes, int n_in,
                              void* d_out, int out_size, void* d_ws, size_t ws_size,
                              hipStream_t stream)
{
  const float* noise   = (const float*)d_in[0];
  const float* frac    = (const float*)d_in[1];
  const float* lengths = (const float*)d_in[2];
  const float* angles  = (const float*)d_in[3];
  const int*   types   = (const int*)d_in[4];
  const int*   numat   = (const int*)d_in[5];
  const int*   ei      = (const int*)d_in[6];
  const int*   ji      = (const int*)d_in[7];
  const int*   kj      = (const int*)d_in[8];
  const float* emb     = (const float*)d_in[9];
  const float* Whz     = (const float*)d_in[10];
  const float* Wedge   = (const float*)d_in[11];
  const float* Wm      = (const float*)d_in[12];
  const float* Wr1     = (const float*)d_in[13];
  const float* Wdown   = (const float*)d_in[14];
  const float* Wcbf    = (const float*)d_in[15];
  const float* Wup     = (const float*)d_in[16];
  const float* Wa      = (const float*)d_in[17];
  const float* Wr2     = (const float*)d_in[18];
  const float* Wh      = (const float*)d_in[19];
  const float* Wsw     = (const float*)d_in[20];
  const float* Wtw     = (const float*)d_in[21];
  const float* Wout    = (const float*)d_in[22];
  const float* Wfc0    = (const float*)d_in[23];
  const float* bfc0    = (const float*)d_in[24];
  const float* Wfc1    = (const float*)d_in[25];
  const float* bfc1    = (const float*)d_in[26];
  const float* Wfc2    = (const float*)d_in[27];
  const float* bfc2    = (const float*)d_in[28];
  float* out = (float*)d_out;

  char* base = (char*)d_ws;
  size_t oo = 0;
  auto ab = [&](size_t bytes)->void*{ void* p = base + oo; oo += bytes; oo = (oo + 63) & ~(size_t)63; return p; };

  float* pos  = (float*)ab((size_t)N_*3*4);
  float* vec  = (float*)ab((size_t)E_*3*4);
  bf16*  rbf  = (bf16*) ab((size_t)E_*64*2);
  float* cbf  = (float*)ab((size_t)T_*16*4);
  float* h    = (float*)ab((size_t)N_*128*4);
  bf16*  hbf  = (bf16*) ab((size_t)N_*128*2);
  bf16*  m    = (bf16*) ab((size_t)E_*128*2);
  bf16*  tmp  = (bf16*) ab((size_t)E_*128*2);   // also reused as ts [E,64]
  bf16*  xbuf = (bf16*) ab((size_t)E_*64*2);
  bf16*  a    = (bf16*) ab((size_t)N_*128*2);
  float* hs   = (float*)ab((size_t)N_*128*4);
  float* ht   = (float*)ab((size_t)N_*128*4);
  float* hW   = (float*)ab((size_t)N_*128*4);
  float* z    = (float*)ab(128*128*4);
  float* f0   = (float*)ab(128*256*4);
  float* f1   = (float*)ab(128*256*4);

  bf16* WedgeT = (bf16*)ab(320*128*2);
  bf16* WmT    = (bf16*)ab((size_t)3*128*128*2);
  bf16* Wr1T   = (bf16*)ab((size_t)3*128*64*2);
  bf16* WdownT = (bf16*)ab((size_t)3*64*128*2);
  bf16* WupT   = (bf16*)ab((size_t)3*128*64*2);
  bf16* WaT    = (bf16*)ab((size_t)3*128*128*2);
  bf16* Wr2T   = (bf16*)ab((size_t)3*128*64*2);
  bf16* WhT    = (bf16*)ab((size_t)3*128*128*2);
  bf16* WsT    = (bf16*)ab((size_t)3*128*128*2);
  bf16* WtT    = (bf16*)ab((size_t)3*128*128*2);
  bf16* WoutT  = (bf16*)ab(128*128*2);

  int* cnt_ji   = (int*)ab((size_t)E_*4);
  int* off_ji   = (int*)ab((size_t)(E_+1)*4);
  int* cur_ji   = (int*)ab((size_t)E_*4);
  int* list_ji  = (int*)ab((size_t)T_*4);
  int* cnt_dst  = (int*)ab((size_t)N_*4);
  int* off_dst  = (int*)ab((size_t)(N_+1)*4);
  int* cur_dst  = (int*)ab((size_t)N_*4);
  int* list_dst = (int*)ab((size_t)E_*4);

  bf16* ts = tmp;

  // ---- weight conversion (2 packed launches) ----
  WPack p1{}, p2{};
  {
    int i = 0;
    p1.d[i++] = {Wedge, WedgeT, 320, 7};
    for(int b=0;b<3;b++) p1.d[i++] = {Wm   + (size_t)b*128*128, WmT   + (size_t)b*128*128, 128, 7};
    for(int b=0;b<3;b++) p1.d[i++] = {Wr1  + (size_t)b*64*128,  Wr1T  + (size_t)b*128*64,   64, 7};
    for(int b=0;b<3;b++) p1.d[i++] = {Wdown+ (size_t)b*128*64,  WdownT+ (size_t)b*64*128,  128, 6};
    for(int b=0;b<3;b++) p1.d[i++] = {Wup  + (size_t)b*64*128,  WupT  + (size_t)b*128*64,   64, 7};
    for(int b=0;b<3;b++) p1.d[i++] = {Wa   + (size_t)b*128*128, WaT   + (size_t)b*128*128, 128, 7};
    int j = 0;
    for(int b=0;b<3;b++) p2.d[j++] = {Wr2  + (size_t)b*64*128,  Wr2T  + (size_t)b*128*64,   64, 7};
    for(int b=0;b<3;b++) p2.d[j++] = {Wh   + (size_t)b*128*128, WhT   + (size_t)b*128*128, 128, 7};
    for(int b=0;b<3;b++) p2.d[j++] = {Wsw  + (size_t)b*128*128, WsT   + (size_t)b*128*128, 128, 7};
    for(int b=0;b<3;b++) p2.d[j++] = {Wtw  + (size_t)b*128*128, WtT   + (size_t)b*128*128, 128, 7};
    p2.d[j++] = {Wout, WoutT, 128, 7};
    wconv_kernel<<<dim3(160,16), 256, 0, stream>>>(p1);
    wconv_kernel<<<dim3(64,13),  256, 0, stream>>>(p2);
  }

  // ---- CSR builds ----
  hipMemsetAsync(cnt_ji, 0, E_*sizeof(int), stream);
  hipMemsetAsync(cnt_dst, 0, N_*sizeof(int), stream);
  hist_kernel<<<T_/256, 256, 0, stream>>>(ji, cnt_ji, T_);
  hist_kernel<<<E_/256, 256, 0, stream>>>(ei + E_, cnt_dst, E_);
  scan_kernel<64><<<1, 1024, 0, stream>>>(cnt_ji, off_ji, cur_ji, E_);
  scan_kernel<4><<<1, 1024, 0, stream>>>(cnt_dst, off_dst, cur_dst, N_);
  fill_kernel<<<T_/256, 256, 0, stream>>>(ji, cur_ji, list_ji, T_);
  fill_kernel<<<E_/256, 256, 0, stream>>>(ei + E_, cur_dst, list_dst, E_);

  // ---- geometry + init ----
  pos_kernel<<<N_/256, 256, 0, stream>>>(frac, lengths, angles, pos);
  edge_kernel<<<E_/4, 256, 0, stream>>>(pos, ei, vec, rbf);
  cbf_kernel<<<T_/16, 256, 0, stream>>>(vec, ji, kj, cbf);
  h0_kernel<<<N_, 128, 0, stream>>>(emb, types, noise, Whz, h, hbf);
  mgemm_m0<<<E_/128, 256, 0, stream>>>(hbf, rbf, ei, WedgeT, m);

  for(int b = 0; b < 3; b++){
    const bf16* WmT_b  = WmT   + (size_t)b*128*128;
    const bf16* Wr1T_b = Wr1T  + (size_t)b*128*64;
    const bf16* WdT_b  = WdownT+ (size_t)b*64*128;
    const float* Wc_b  = Wcbf  + (size_t)b*16*64;
    const bf16* WuT_b  = WupT  + (size_t)b*128*64;
    const bf16* WaT_b  = WaT   + (size_t)b*128*128;
    const bf16* Wr2T_b = Wr2T  + (size_t)b*128*64;
    const bf16* WhT_b  = WhT   + (size_t)b*128*128;
    const bf16* WsT_b  = WsT   + (size_t)b*128*128;
    const bf16* WtT_b  = WtT   + (size_t)b*128*128;

    // tmp = silu(m @ Wm) * (rbf @ Wr1)
    mgemm<128,128,0,true,64,false><<<E_/128, 256, 0, stream>>>(m, WmT_b, rbf, Wr1T_b, tmp, nullptr);
    // x = tmp @ Wdown
    mgemm<128,64,0,false,0,false><<<E_/128, 256, 0, stream>>>(tmp, WdT_b, nullptr, nullptr, xbuf, nullptr);
    // ts = seg(x[kj] * (cbf@Wcbf), ji)   (overwrites tmp)
    tsum_kernel<<<E_/4, 256, 0, stream>>>(off_ji, list_ji, kj, cbf, xbuf, Wc_b, ts);
    // m += silu(ts @ Wup)
    mgemm<64,128,2,false,0,false><<<E_/128, 256, 0, stream>>>(ts, WuT_b, nullptr, nullptr, m, nullptr);
    // tmp = silu(m @ Wa) * (rbf @ Wr2)
    mgemm<128,128,0,true,64,false><<<E_/128, 256, 0, stream>>>(m, WaT_b, rbf, Wr2T_b, tmp, nullptr);
    // a = seg(tmp, dst)
    asum_kernel<<<N_, 128, 0, stream>>>(off_dst, list_dst, tmp, a);
    // h += silu(a @ Wh)  (fp32 master + bf16 mirror)
    mgemm<128,128,3,false,0,false><<<N_/128, 256, 0, stream>>>(a, WhT_b, nullptr, nullptr, hbf, h);
    // hs = h @ Ws ; ht = h @ Wt  (fp32 out)
    mgemm<128,128,0,false,0,true><<<N_/128, 256, 0, stream>>>(hbf, WsT_b, nullptr, nullptr, hs, nullptr);
    mgemm<128,128,0,false,0,true><<<N_/128, 256, 0, stream>>>(hbf, WtT_b, nullptr, nullptr, ht, nullptr);
    // m += silu(hs[src] + ht[dst])
    scat_kernel<<<E_/2, 256, 0, stream>>>(ei, hs, ht, m);
  }

  // ---- readout ----
  mgemm<128,128,0,false,0,true><<<N_/128, 256, 0, stream>>>(hbf, WoutT, nullptr, nullptr, hW, nullptr);
  zred_kernel<<<128, 128, 0, stream>>>(hW, numat, z);
  gemm_k<32,128,3,false><<<dim3(4,2), 256, 0, stream>>>(z,  Wfc0, 128, f0, 256, bfc0);
  gemm_k<32,128,3,false><<<dim3(4,2), 256, 0, stream>>>(f0, Wfc1, 256, f1, 256, bfc1);
  gemm_k<32,128,4,true ><<<dim3(4,2), 256, 0, stream>>>(f1, Wfc2, 256, out, 230, bfc2);
}

// Round 3
// 816.693 us; speedup vs baseline: 2.2354x; 1.0790x over previous
//
#include <hip/hip_runtime.h>
#include <hip/hip_bf16.h>
#include <math.h>

constexpr int B_ = 128, N_ = 4096, E_ = 65536, T_ = 262144;

typedef __attribute__((ext_vector_type(8))) __bf16 bf16x8;
typedef __attribute__((ext_vector_type(4))) float f32x4;
typedef __hip_bfloat16 bf16;

__device__ __forceinline__ float silu_f(float x){ return x / (1.0f + __expf(-x)); }
__device__ __forceinline__ float bf2f(bf16 v){ return __bfloat162float(v); }
__device__ __forceinline__ bf16  f2bf(float v){ return __float2bfloat16(v); }
__device__ __forceinline__ float bfx(bf16x8 v, int j){ __bf16 t = v[j]; return (float)t; }

// ================= CSR build =================
__global__ void hist_kernel(const int* __restrict__ idx, int* __restrict__ cnt, int n){
  int i = blockIdx.x*256 + threadIdx.x;
  if(i < n) atomicAdd(&cnt[idx[i]], 1);
}
__global__ void fill_kernel(const int* __restrict__ idx, int* __restrict__ cur, int* __restrict__ list, int n){
  int i = blockIdx.x*256 + threadIdx.x;
  if(i < n){ int p = atomicAdd(&cur[idx[i]], 1); list[p] = i; }
}
template<int PER>
__global__ __launch_bounds__(1024) void scan_kernel(const int* __restrict__ cnt, int* __restrict__ offs,
                                                    int* __restrict__ cur, int n){
  __shared__ int sh[1024];
  int t = threadIdx.x;
  int base = t * PER;
  int s = 0;
  for(int i = 0; i < PER; i++) s += cnt[base + i];
  sh[t] = s;
  __syncthreads();
  for(int d = 1; d < 1024; d <<= 1){
    int v = (t >= d) ? sh[t - d] : 0;
    __syncthreads();
    sh[t] += v;
    __syncthreads();
  }
  int run = sh[t] - s;
  for(int i = 0; i < PER; i++){
    offs[base + i] = run; cur[base + i] = run;
    run += cnt[base + i];
  }
  if(t == 1023) offs[n] = run;
}

// ================= geometry =================
__global__ void pos_kernel(const float* __restrict__ frac, const float* __restrict__ lengths,
                           const float* __restrict__ angles, float* __restrict__ pos){
  int i = blockIdx.x*256 + threadIdx.x;
  if(i >= N_) return;
  int b = i >> 5;
  const float d2r = 0.017453292519943295f;
  float La = lengths[b*3+0], Lb = lengths[b*3+1], Lc = lengths[b*3+2];
  float al = angles[b*3+0]*d2r, be = angles[b*3+1]*d2r, ga = angles[b*3+2]*d2r;
  float ca = cosf(al), cb = cosf(be), cg = cosf(ga), sg = sinf(ga);
  float cx = cb, cy = (ca - cb*cg) / sg;
  float cz = sqrtf(fmaxf(1.0f - cx*cx - cy*cy, 1e-8f));
  float l00 = La, l10 = Lb*cg, l11 = Lb*sg, l20 = Lc*cx, l21 = Lc*cy, l22 = Lc*cz;
  float fx = frac[i*3], fy = frac[i*3+1], fz = frac[i*3+2];
  pos[i*3+0] = fx*l00 + fy*l10 + fz*l20;
  pos[i*3+1] = fy*l11 + fz*l21;
  pos[i*3+2] = fz*l22;
}

__global__ __launch_bounds__(256) void edge_kernel(const float* __restrict__ pos, const int* __restrict__ ei,
                                                   float* __restrict__ vec, bf16* __restrict__ rbf){
  int e = blockIdx.x*4 + (threadIdx.x >> 6);
  int lane = threadIdx.x & 63;
  int s = ei[e], d = ei[E_ + e];
  float vx = pos[d*3+0]-pos[s*3+0];
  float vy = pos[d*3+1]-pos[s*3+1];
  float vz = pos[d*3+2]-pos[s*3+2];
  float dd = sqrtf(vx*vx + vy*vy + vz*vz + 1e-12f);
  float dsc = dd * (1.0f/7.0f);
  float env = 0.0f;
  if(dsc < 1.0f){
    float d2 = dsc*dsc, d5 = d2*d2*dsc;
    env = 1.0f - 21.0f*d5 + 35.0f*d5*dsc - 15.0f*d5*d2;
  }
  float arg = (float)(lane+1) * 3.14159265358979f * dsc;
  rbf[(size_t)e*64 + lane] = f2bf(env * 0.5345224838248488f * sinf(arg) / dd);
  if(lane < 3){ vec[e*3+lane] = (lane==0) ? vx : (lane==1 ? vy : vz); }
}

// ================= tprep: sorted triplet streams =================
// At CSR position idx (sorted by ji): kj_s[idx]=kj[t], cbf_s[idx][s]=T_s(clip(cos angle)) in bf16.
// cos(s*arccos(x)) == Chebyshev T_s(x): recurrence, no trig.
__global__ __launch_bounds__(256) void tprep_kernel(const int* __restrict__ list, const int* __restrict__ ji,
                                                    const int* __restrict__ kj, const float* __restrict__ vec,
                                                    bf16* __restrict__ cbf_s, int* __restrict__ kj_s){
  int idx = blockIdx.x*256 + threadIdx.x;
  int t = list[idx];
  int a = ji[t], b = kj[t];
  kj_s[idx] = b;
  float ax = vec[a*3], ay = vec[a*3+1], az = vec[a*3+2];
  float bx = vec[b*3], by = vec[b*3+1], bz = vec[b*3+2];
  float dot = ax*bx + ay*by + az*bz;
  float na = sqrtf(ax*ax + ay*ay + az*az);
  float nb = sqrtf(bx*bx + by*by + bz*bz);
  float x = dot / (na*nb + 1e-9f);
  x = fminf(fmaxf(x, -1.0f + 1e-6f), 1.0f - 1e-6f);
  float c[16];
  c[0] = 1.0f; c[1] = x;
  float x2 = 2.0f * x;
  #pragma unroll
  for(int s = 2; s < 16; s++) c[s] = x2*c[s-1] - c[s-2];
  bf16x8 o0, o1;
  #pragma unroll
  for(int j = 0; j < 8; j++){ o0[j] = (__bf16)c[j]; o1[j] = (__bf16)c[8+j]; }
  *(bf16x8*)&cbf_s[(size_t)idx*16]     = o0;
  *(bf16x8*)&cbf_s[(size_t)idx*16 + 8] = o1;
}

// ================= weight transpose+convert: fp32 [K,N] -> bf16 [N][K] =================
struct WDesc { const float* src; bf16* dst; int K; int shN; };
struct WPack { WDesc d[16]; };
__global__ __launch_bounds__(256) void wconv_kernel(WPack p){
  WDesc w = p.d[blockIdx.y];
  int idx = blockIdx.x*256 + threadIdx.x;
  int NN = 1 << w.shN;
  if(idx >= w.K * NN) return;
  int k = idx >> w.shN, c = idx & (NN - 1);
  w.dst[(size_t)c * w.K + k] = f2bf(w.src[idx]);
}

// ================= h init =================
__global__ __launch_bounds__(128) void h0_kernel(const float* __restrict__ emb, const int* __restrict__ types,
                                                 const float* __restrict__ noise, const float* __restrict__ Whz,
                                                 float* __restrict__ h, bf16* __restrict__ hbf){
  __shared__ float arow[129];
  int i = blockIdx.x;
  int c = threadIdx.x;
  arow[c] = emb[(size_t)types[i]*128 + c];
  if(c == 0) arow[128] = noise[i >> 5];
  __syncthreads();
  float acc = 0.f;
  for(int k = 0; k < 129; k++) acc += arow[k] * Whz[(size_t)k*128 + c];
  float v = silu_f(acc);
  h[(size_t)i*128 + c] = v;
  hbf[(size_t)i*128 + c] = f2bf(v);
}

// ================= MFMA GEMM core =================
template<int KK, int FM>
__device__ __forceinline__ void kloop(const bf16* __restrict__ A, const bf16* __restrict__ W,
                                      int rowA0, int colW0, int lr, int lk, f32x4 (*acc)[4])
{
  #pragma unroll
  for(int k0 = 0; k0 < KK; k0 += 32){
    bf16x8 af[FM], bv[4];
    #pragma unroll
    for(int fm = 0; fm < FM; fm++)
      af[fm] = *(const bf16x8*)(A + (size_t)(rowA0 + fm*16 + lr)*KK + k0 + lk*8);
    #pragma unroll
    for(int fn = 0; fn < 4; fn++)
      bv[fn] = *(const bf16x8*)(W + (size_t)(colW0 + fn*16 + lr)*KK + k0 + lk*8);
    #pragma unroll
    for(int fm = 0; fm < FM; fm++)
      #pragma unroll
      for(int fn = 0; fn < 4; fn++)
        acc[fm][fn] = __builtin_amdgcn_mfma_f32_16x16x32_bf16(af[fm], bv[fn], acc[fm][fn], 0, 0, 0);
  }
}

// EPI: 0=store, 2=bf16 C += silu(x), 3=fp32 Res += silu(x) and bf16 mirror store
template<int K1, int N, int EPI, bool DUAL, int K2, bool OUTF32>
__global__ __launch_bounds__(256, 2) void mgemm(
    const bf16* __restrict__ A, const bf16* __restrict__ W,
    const bf16* __restrict__ A2, const bf16* __restrict__ W2,
    void* __restrict__ Cout, float* __restrict__ Res)
{
  constexpr int WC = N/64, WR = 4/WC, RPW = 128/WR, FM = RPW/16;
  const int tid = threadIdx.x;
  const int wid = tid >> 6, lane = tid & 63;
  const int wr = wid / WC, wc = wid % WC;
  const int lr = lane & 15, lk = lane >> 4;
  const int rowA0 = blockIdx.x*128 + wr*RPW;
  const int colW0 = wc*64;

  f32x4 acc[FM][4];
  #pragma unroll
  for(int i = 0; i < FM; i++)
    #pragma unroll
    for(int j = 0; j < 4; j++) acc[i][j] = (f32x4){0.f,0.f,0.f,0.f};

  kloop<K1, FM>(A, W, rowA0, colW0, lr, lk, acc);

  float sv[FM][4][4];
  if constexpr (DUAL){
    #pragma unroll
    for(int i = 0; i < FM; i++)
      #pragma unroll
      for(int j = 0; j < 4; j++){
        #pragma unroll
        for(int r = 0; r < 4; r++) sv[i][j][r] = silu_f(acc[i][j][r]);
        acc[i][j] = (f32x4){0.f,0.f,0.f,0.f};
      }
    kloop<(DUAL ? K2 : 32), FM>(A2, W2, rowA0, colW0, lr, lk, acc);
  }

  #pragma unroll
  for(int fm = 0; fm < FM; fm++){
    #pragma unroll
    for(int fn = 0; fn < 4; fn++){
      #pragma unroll
      for(int r = 0; r < 4; r++){
        int row = rowA0 + fm*16 + lk*4 + r;
        int col = colW0 + fn*16 + lr;
        size_t off = (size_t)row * N + col;
        float x = acc[fm][fn][r];
        if constexpr (DUAL) x = sv[fm][fn][r] * x;
        if constexpr (EPI == 2){
          bf16* C = (bf16*)Cout;
          x = bf2f(C[off]) + silu_f(x);
          C[off] = f2bf(x);
        } else if constexpr (EPI == 3){
          x = Res[off] + silu_f(x);
          Res[off] = x;
          ((bf16*)Cout)[off] = f2bf(x);
        } else {
          if constexpr (OUTF32) ((float*)Cout)[off] = x;
          else ((bf16*)Cout)[off] = f2bf(x);
        }
      }
    }
  }
}

// ===== fused: tmp = silu(m@Wm)*(rbf@Wr1) [kept in LDS]; x = tmp@Wdown ([E,64] bf16 out) =====
__global__ __launch_bounds__(256, 2) void mgemm_dd(
    const bf16* __restrict__ m, const bf16* __restrict__ Wm /*[128][128]*/,
    const bf16* __restrict__ rbf, const bf16* __restrict__ Wr1 /*[128][64]*/,
    const bf16* __restrict__ Wd /*[64][128]*/, bf16* __restrict__ xout)
{
  __shared__ __bf16 sT[128*128];
  const int tid = threadIdx.x;
  const int wid = tid >> 6, lane = tid & 63;
  const int wr = wid >> 1, wc = wid & 1;
  const int lr = lane & 15, lk = lane >> 4;
  const int row0 = blockIdx.x*128;

  f32x4 acc[4][4];
  #pragma unroll
  for(int i = 0; i < 4; i++)
    #pragma unroll
    for(int j = 0; j < 4; j++) acc[i][j] = (f32x4){0.f,0.f,0.f,0.f};
  kloop<128,4>(m, Wm, row0 + wr*64, wc*64, lr, lk, acc);
  float sv[4][4][4];
  #pragma unroll
  for(int i = 0; i < 4; i++)
    #pragma unroll
    for(int j = 0; j < 4; j++){
      #pragma unroll
      for(int r = 0; r < 4; r++) sv[i][j][r] = silu_f(acc[i][j][r]);
      acc[i][j] = (f32x4){0.f,0.f,0.f,0.f};
    }
  kloop<64,4>(rbf, Wr1, row0 + wr*64, wc*64, lr, lk, acc);

  // write tmp tile to LDS, XOR-swizzled (col ^ ((row&7)<<3)) for conflict-free b128 reads
  #pragma unroll
  for(int fm = 0; fm < 4; fm++)
    #pragma unroll
    for(int fn = 0; fn < 4; fn++)
      #pragma unroll
      for(int r = 0; r < 4; r++){
        int row = wr*64 + fm*16 + lk*4 + r;
        int col = wc*64 + fn*16 + lr;
        sT[row*128 + (col ^ ((row & 7) << 3))] = (__bf16)(sv[fm][fn][r] * acc[fm][fn][r]);
      }
  __syncthreads();

  // GEMM2: x[128 rows][64] = tmp @ Wd^T ; wave wid owns 32 rows
  f32x4 a2[2][4];
  #pragma unroll
  for(int i = 0; i < 2; i++)
    #pragma unroll
    for(int j = 0; j < 4; j++) a2[i][j] = (f32x4){0.f,0.f,0.f,0.f};
  #pragma unroll
  for(int k0 = 0; k0 < 128; k0 += 32){
    bf16x8 af[2], bv[4];
    #pragma unroll
    for(int fm = 0; fm < 2; fm++){
      int row = wid*32 + fm*16 + lr;
      af[fm] = *(const bf16x8*)&sT[row*128 + ((k0 + lk*8) ^ ((row & 7) << 3))];
    }
    #pragma unroll
    for(int fn = 0; fn < 4; fn++)
      bv[fn] = *(const bf16x8*)(Wd + (size_t)(fn*16 + lr)*128 + k0 + lk*8);
    #pragma unroll
    for(int fm = 0; fm < 2; fm++)
      #pragma unroll
      for(int fn = 0; fn < 4; fn++)
        a2[fm][fn] = __builtin_amdgcn_mfma_f32_16x16x32_bf16(af[fm], bv[fn], a2[fm][fn], 0, 0, 0);
  }
  #pragma unroll
  for(int fm = 0; fm < 2; fm++)
    #pragma unroll
    for(int fn = 0; fn < 4; fn++)
      #pragma unroll
      for(int r = 0; r < 4; r++){
        int row = wid*32 + fm*16 + lk*4 + r;
        int col = fn*16 + lr;
        xout[(size_t)(row0 + row)*64 + col] = f2bf(a2[fm][fn][r]);
      }
}

// ===== fused hs/ht: grid.y picks Ws vs Wt =====
__global__ __launch_bounds__(256, 2) void mgemm_st(
    const bf16* __restrict__ hbf, const bf16* __restrict__ WstT /*[2][128][128]*/,
    bf16* __restrict__ hs, bf16* __restrict__ ht)
{
  const bf16* W = WstT + (size_t)blockIdx.y*128*128;
  bf16* out = blockIdx.y ? ht : hs;
  const int tid = threadIdx.x;
  const int wid = tid >> 6, lane = tid & 63;
  const int wr = wid >> 1, wc = wid & 1;
  const int lr = lane & 15, lk = lane >> 4;
  const int rowA0 = blockIdx.x*128 + wr*64;
  f32x4 acc[4][4];
  #pragma unroll
  for(int i = 0; i < 4; i++)
    #pragma unroll
    for(int j = 0; j < 4; j++) acc[i][j] = (f32x4){0.f,0.f,0.f,0.f};
  kloop<128,4>(hbf, W, rowA0, wc*64, lr, lk, acc);
  #pragma unroll
  for(int fm = 0; fm < 4; fm++)
    #pragma unroll
    for(int fn = 0; fn < 4; fn++)
      #pragma unroll
      for(int r = 0; r < 4; r++){
        int row = rowA0 + fm*16 + lk*4 + r;
        int col = wc*64 + fn*16 + lr;
        out[(size_t)row*128 + col] = f2bf(acc[fm][fn][r]);
      }
}

// m0: A = concat(h[src], h[dst], rbf) gathered, K=320, N=128
__global__ __launch_bounds__(256, 2) void mgemm_m0(
    const bf16* __restrict__ hb, const bf16* __restrict__ rbf, const int* __restrict__ ei,
    const bf16* __restrict__ Wt /*[128][320]*/, bf16* __restrict__ mout)
{
  const int tid = threadIdx.x;
  const int wid = tid >> 6, lane = tid & 63;
  const int wr = wid >> 1, wc = wid & 1;
  const int lr = lane & 15, lk = lane >> 4;
  const int e0 = blockIdx.x*128 + wr*64;

  int esrc[4], edst[4];
  #pragma unroll
  for(int fm = 0; fm < 4; fm++){
    int e = e0 + fm*16 + lr;
    esrc[fm] = ei[e]; edst[fm] = ei[E_ + e];
  }

  f32x4 acc[4][4];
  #pragma unroll
  for(int i = 0; i < 4; i++)
    #pragma unroll
    for(int j = 0; j < 4; j++) acc[i][j] = (f32x4){0.f,0.f,0.f,0.f};

  #pragma unroll
  for(int ks = 0; ks < 10; ks++){
    const int k0 = ks*32;
    bf16x8 af[4], bv[4];
    #pragma unroll
    for(int fm = 0; fm < 4; fm++){
      const bf16* p;
      if(k0 < 128)      p = hb + (size_t)esrc[fm]*128 + k0;
      else if(k0 < 256) p = hb + (size_t)edst[fm]*128 + (k0 - 128);
      else              p = rbf + (size_t)(e0 + fm*16 + lr)*64 + (k0 - 256);
      af[fm] = *(const bf16x8*)(p + lk*8);
    }
    #pragma unroll
    for(int fn = 0; fn < 4; fn++)
      bv[fn] = *(const bf16x8*)(Wt + (size_t)(wc*64 + fn*16 + lr)*320 + k0 + lk*8);
    #pragma unroll
    for(int fm = 0; fm < 4; fm++)
      #pragma unroll
      for(int fn = 0; fn < 4; fn++)
        acc[fm][fn] = __builtin_amdgcn_mfma_f32_16x16x32_bf16(af[fm], bv[fn], acc[fm][fn], 0, 0, 0);
  }

  #pragma unroll
  for(int fm = 0; fm < 4; fm++)
    #pragma unroll
    for(int fn = 0; fn < 4; fn++)
      #pragma unroll
      for(int r = 0; r < 4; r++){
        int row = e0 + fm*16 + lk*4 + r;
        int col = wc*64 + fn*16 + lr;
        mout[(size_t)row*128 + col] = f2bf(silu_f(acc[fm][fn][r]));
      }
}

// ================= triplet segsum (sorted streams) =================
__global__ __launch_bounds__(256) void tsum_kernel(const int* __restrict__ offs, const int* __restrict__ kj_s,
                                                   const bf16* __restrict__ cbf_s, const bf16* __restrict__ x,
                                                   const float* __restrict__ Wc, bf16* __restrict__ ts){
  int e = blockIdx.x*4 + (threadIdx.x >> 6);
  int lane = threadIdx.x & 63;
  float wcv[16];
  #pragma unroll
  for(int s = 0; s < 16; s++) wcv[s] = Wc[s*64 + lane];
  float acc = 0.f;
  int b0 = offs[e], b1 = offs[e+1];
  for(int idx = b0; idx < b1; ++idx){
    int k = kj_s[idx];
    bf16x8 c0 = *(const bf16x8*)&cbf_s[(size_t)idx*16];
    bf16x8 c1 = *(const bf16x8*)&cbf_s[(size_t)idx*16 + 8];
    float cw = 0.f;
    #pragma unroll
    for(int j = 0; j < 8; j++) cw += bfx(c0,j)*wcv[j] + bfx(c1,j)*wcv[8+j];
    acc += bf2f(x[(size_t)k*64 + lane]) * cw;
  }
  ts[(size_t)e*64 + lane] = f2bf(acc);
}

// ================= edge->atom segsum (16 lanes x bf16x8 per atom) =================
__global__ __launch_bounds__(256) void asum_kernel(const int* __restrict__ offs, const int* __restrict__ list,
                                                   const bf16* __restrict__ buf, bf16* __restrict__ a){
  int g = blockIdx.x*256 + threadIdx.x;
  int i = g >> 4, c8 = g & 15;
  float acc[8];
  #pragma unroll
  for(int j = 0; j < 8; j++) acc[j] = 0.f;
  int b0 = offs[i], b1 = offs[i+1];
  for(int idx = b0; idx < b1; ++idx){
    bf16x8 v = *(const bf16x8*)&buf[(size_t)list[idx]*128 + c8*8];
    #pragma unroll
    for(int j = 0; j < 8; j++) acc[j] += bfx(v,j);
  }
  bf16x8 o;
  #pragma unroll
  for(int j = 0; j < 8; j++) o[j] = (__bf16)acc[j];
  *(bf16x8*)&a[(size_t)i*128 + c8*8] = o;
}

// ================= m[e] += silu(hs[src]+ht[dst]) (bf16x8) =================
__global__ __launch_bounds__(256) void scat_kernel(const int* __restrict__ ei, const bf16* __restrict__ hs,
                                                   const bf16* __restrict__ ht, bf16* __restrict__ m){
  int g = blockIdx.x*256 + threadIdx.x;
  int e = g >> 4, c8 = g & 15;
  int s = ei[e], d = ei[E_ + e];
  bf16x8 va = *(const bf16x8*)&hs[(size_t)s*128 + c8*8];
  bf16x8 vb = *(const bf16x8*)&ht[(size_t)d*128 + c8*8];
  bf16x8 vm = *(bf16x8*)&m[(size_t)e*128 + c8*8];
  #pragma unroll
  for(int j = 0; j < 8; j++)
    vm[j] = (__bf16)(bfx(vm,j) + silu_f(bfx(va,j) + bfx(vb,j)));
  *(bf16x8*)&m[(size_t)e*128 + c8*8] = vm;
}

// ================= z mean =================
__global__ __launch_bounds__(128) void zred_kernel(const float* __restrict__ hW, const int* __restrict__ numat,
                                                   float* __restrict__ z){
  int b = blockIdx.x, c = threadIdx.x;
  float s = 0.f;
  for(int i = 0; i < 32; i++) s += hW[((size_t)b*32 + i)*128 + c];
  z[(size_t)b*128 + c] = s / (float)numat[b];
}

// ================= fp32 tiled GEMM (final MLP only) =================
template<int BM,int BN,int EPI,bool CGUARD>
__global__ __launch_bounds__(256) void gemm_k(
    const float* __restrict__ A, const float* __restrict__ W, int K,
    float* __restrict__ C, int ncols, const float* __restrict__ bias)
{
  constexpr int CGN = BN/4;
  constexpr int TG  = 256/CGN;
  constexpr int RT  = BM/TG;
  constexpr int LDA = BM + 4;
  __shared__ float sA[32*LDA];
  __shared__ float sW[32*BN];
  const int tid = threadIdx.x;
  const int tx = tid % CGN, ty = tid / CGN;
  const int row0 = blockIdx.x * BM;
  const int col0 = blockIdx.y * BN;
  float acc[RT][4];
  #pragma unroll
  for(int r=0;r<RT;r++){ acc[r][0]=0.f; acc[r][1]=0.f; acc[r][2]=0.f; acc[r][3]=0.f; }

  for(int k0 = 0; k0 < K; k0 += 32){
    #pragma unroll
    for(int i=0;i<(BM*32)/256;i++){
      int idx = i*256 + tid; int r = idx >> 5, k = idx & 31;
      sA[k*LDA + r] = A[(size_t)(row0+r)*K + (k0+k)];
    }
    #pragma unroll
    for(int i=0;i<(32*BN)/256;i++){
      int idx = i*256 + tid; int k = idx / BN, c = idx % BN;
      float w = 0.f;
      if(!CGUARD || (col0 + c) < ncols) w = W[(size_t)(k0+k)*ncols + col0 + c];
      sW[idx] = w;
    }
    __syncthreads();
    #pragma unroll
    for(int kk=0;kk<32;kk++){
      float4 wv = *(const float4*)&sW[kk*BN + tx*4];
      #pragma unroll
      for(int r4=0;r4<RT/4;r4++){
        float4 av = *(const float4*)&sA[kk*LDA + ty*RT + r4*4];
        float aa[4] = {av.x, av.y, av.z, av.w};
        #pragma unroll
        for(int rr=0;rr<4;rr++){
          int r = r4*4 + rr;
          acc[r][0] += aa[rr]*wv.x; acc[r][1] += aa[rr]*wv.y;
          acc[r][2] += aa[rr]*wv.z; acc[r][3] += aa[rr]*wv.w;
        }
      }
    }
    __syncthreads();
  }

  #pragma unroll
  for(int r=0;r<RT;r++){
    size_t off = (size_t)(row0 + ty*RT + r)*ncols + col0 + tx*4;
    #pragma unroll
    for(int j=0;j<4;j++){
      int cc = col0 + tx*4 + j;
      bool ok = (!CGUARD) || (cc < ncols);
      float x = acc[r][j];
      if(EPI == 3) x = fmaxf(x + (ok ? bias[cc] : 0.f), 0.f);
      else if(EPI == 4) x = x + (ok ? bias[cc] : 0.f);
      if(ok) C[off+j] = x;
    }
  }
}

extern "C" void kernel_launch(void* const* d_in, const int* in_sizes, int n_in,
                              void* d_out, int out_size, void* d_ws, size_t ws_size,
                              hipStream_t stream)
{
  const float* noise   = (const float*)d_in[0];
  const float* frac    = (const float*)d_in[1];
  const float* lengths = (const float*)d_in[2];
  const float* angles  = (const float*)d_in[3];
  const int*   types   = (const int*)d_in[4];
  const int*   numat   = (const int*)d_in[5];
  const int*   ei      = (const int*)d_in[6];
  const int*   ji      = (const int*)d_in[7];
  const int*   kj      = (const int*)d_in[8];
  const float* emb     = (const float*)d_in[9];
  const float* Whz     = (const float*)d_in[10];
  const float* Wedge   = (const float*)d_in[11];
  const float* Wm      = (const float*)d_in[12];
  const float* Wr1     = (const float*)d_in[13];
  const float* Wdown   = (const float*)d_in[14];
  const float* Wcbf    = (const float*)d_in[15];
  const float* Wup     = (const float*)d_in[16];
  const float* Wa      = (const float*)d_in[17];
  const float* Wr2     = (const float*)d_in[18];
  const float* Wh      = (const float*)d_in[19];
  const float* Wsw     = (const float*)d_in[20];
  const float* Wtw     = (const float*)d_in[21];
  const float* Wout    = (const float*)d_in[22];
  const float* Wfc0    = (const float*)d_in[23];
  const float* bfc0    = (const float*)d_in[24];
  const float* Wfc1    = (const float*)d_in[25];
  const float* bfc1    = (const float*)d_in[26];
  const float* Wfc2    = (const float*)d_in[27];
  const float* bfc2    = (const float*)d_in[28];
  float* out = (float*)d_out;

  char* base = (char*)d_ws;
  size_t oo = 0;
  auto ab = [&](size_t bytes)->void*{ void* p = base + oo; oo += bytes; oo = (oo + 63) & ~(size_t)63; return p; };

  float* pos   = (float*)ab((size_t)N_*3*4);
  float* vec   = (float*)ab((size_t)E_*3*4);
  bf16*  rbf   = (bf16*) ab((size_t)E_*64*2);
  bf16*  cbf_s = (bf16*) ab((size_t)T_*16*2);
  int*   kj_s  = (int*)  ab((size_t)T_*4);
  float* h     = (float*)ab((size_t)N_*128*4);
  bf16*  hbf   = (bf16*) ab((size_t)N_*128*2);
  bf16*  m     = (bf16*) ab((size_t)E_*128*2);
  bf16*  tmp   = (bf16*) ab((size_t)E_*128*2);   // dualWa out; also aliased as ts [E,64]
  bf16*  xbuf  = (bf16*) ab((size_t)E_*64*2);
  bf16*  a     = (bf16*) ab((size_t)N_*128*2);
  bf16*  hsb   = (bf16*) ab((size_t)N_*128*2);
  bf16*  htb   = (bf16*) ab((size_t)N_*128*2);
  float* hW    = (float*)ab((size_t)N_*128*4);
  float* z     = (float*)ab(128*128*4);
  float* f0    = (float*)ab(128*256*4);
  float* f1    = (float*)ab(128*256*4);

  bf16* WedgeT = (bf16*)ab(320*128*2);
  bf16* WmT    = (bf16*)ab((size_t)3*128*128*2);
  bf16* Wr1T   = (bf16*)ab((size_t)3*128*64*2);
  bf16* WdownT = (bf16*)ab((size_t)3*64*128*2);
  bf16* WupT   = (bf16*)ab((size_t)3*128*64*2);
  bf16* WaT    = (bf16*)ab((size_t)3*128*128*2);
  bf16* Wr2T   = (bf16*)ab((size_t)3*128*64*2);
  bf16* WhT    = (bf16*)ab((size_t)3*128*128*2);
  bf16* WstT   = (bf16*)ab((size_t)3*2*128*128*2);
  bf16* WoutT  = (bf16*)ab(128*128*2);

  int* cnt_ji   = (int*)ab((size_t)E_*4);
  int* off_ji   = (int*)ab((size_t)(E_+1)*4);
  int* cur_ji   = (int*)ab((size_t)E_*4);
  int* list_ji  = (int*)ab((size_t)T_*4);
  int* cnt_dst  = (int*)ab((size_t)N_*4);
  int* off_dst  = (int*)ab((size_t)(N_+1)*4);
  int* cur_dst  = (int*)ab((size_t)N_*4);
  int* list_dst = (int*)ab((size_t)E_*4);

  bf16* ts = tmp;

  // ---- weight conversion ----
  WPack p1{}, p2{};
  {
    int i = 0;
    p1.d[i++] = {Wedge, WedgeT, 320, 7};
    for(int b=0;b<3;b++) p1.d[i++] = {Wm   + (size_t)b*128*128, WmT   + (size_t)b*128*128, 128, 7};
    for(int b=0;b<3;b++) p1.d[i++] = {Wr1  + (size_t)b*64*128,  Wr1T  + (size_t)b*128*64,   64, 7};
    for(int b=0;b<3;b++) p1.d[i++] = {Wdown+ (size_t)b*128*64,  WdownT+ (size_t)b*64*128,  128, 6};
    for(int b=0;b<3;b++) p1.d[i++] = {Wup  + (size_t)b*64*128,  WupT  + (size_t)b*128*64,   64, 7};
    for(int b=0;b<3;b++) p1.d[i++] = {Wa   + (size_t)b*128*128, WaT   + (size_t)b*128*128, 128, 7};
    int j = 0;
    for(int b=0;b<3;b++) p2.d[j++] = {Wr2  + (size_t)b*64*128,  Wr2T  + (size_t)b*128*64,   64, 7};
    for(int b=0;b<3;b++) p2.d[j++] = {Wh   + (size_t)b*128*128, WhT   + (size_t)b*128*128, 128, 7};
    for(int b=0;b<3;b++) p2.d[j++] = {Wsw  + (size_t)b*128*128, WstT  + (size_t)b*2*128*128,            128, 7};
    for(int b=0;b<3;b++) p2.d[j++] = {Wtw  + (size_t)b*128*128, WstT  + (size_t)b*2*128*128 + 128*128,  128, 7};
    p2.d[j++] = {Wout, WoutT, 128, 7};
    wconv_kernel<<<dim3(160,16), 256, 0, stream>>>(p1);
    wconv_kernel<<<dim3(64,13),  256, 0, stream>>>(p2);
  }

  // ---- CSR builds ----
  hipMemsetAsync(cnt_ji, 0, E_*sizeof(int), stream);
  hipMemsetAsync(cnt_dst, 0, N_*sizeof(int), stream);
  hist_kernel<<<T_/256, 256, 0, stream>>>(ji, cnt_ji, T_);
  hist_kernel<<<E_/256, 256, 0, stream>>>(ei + E_, cnt_dst, E_);
  scan_kernel<64><<<1, 1024, 0, stream>>>(cnt_ji, off_ji, cur_ji, E_);
  scan_kernel<4><<<1, 1024, 0, stream>>>(cnt_dst, off_dst, cur_dst, N_);
  fill_kernel<<<T_/256, 256, 0, stream>>>(ji, cur_ji, list_ji, T_);
  fill_kernel<<<E_/256, 256, 0, stream>>>(ei + E_, cur_dst, list_dst, E_);

  // ---- geometry + init ----
  pos_kernel<<<N_/256, 256, 0, stream>>>(frac, lengths, angles, pos);
  edge_kernel<<<E_/4, 256, 0, stream>>>(pos, ei, vec, rbf);
  tprep_kernel<<<T_/256, 256, 0, stream>>>(list_ji, ji, kj, vec, cbf_s, kj_s);
  h0_kernel<<<N_, 128, 0, stream>>>(emb, types, noise, Whz, h, hbf);
  mgemm_m0<<<E_/128, 256, 0, stream>>>(hbf, rbf, ei, WedgeT, m);

  for(int b = 0; b < 3; b++){
    const bf16* WmT_b  = WmT   + (size_t)b*128*128;
    const bf16* Wr1T_b = Wr1T  + (size_t)b*128*64;
    const bf16* WdT_b  = WdownT+ (size_t)b*64*128;
    const float* Wc_b  = Wcbf  + (size_t)b*16*64;
    const bf16* WuT_b  = WupT  + (size_t)b*128*64;
    const bf16* WaT_b  = WaT   + (size_t)b*128*128;
    const bf16* Wr2T_b = Wr2T  + (size_t)b*128*64;
    const bf16* WhT_b  = WhT   + (size_t)b*128*128;
    const bf16* WstT_b = WstT  + (size_t)b*2*128*128;

    // x = (silu(m@Wm)*(rbf@Wr1)) @ Wdown   — tmp lives in LDS only
    mgemm_dd<<<E_/128, 256, 0, stream>>>(m, WmT_b, rbf, Wr1T_b, WdT_b, xbuf);
    // ts = seg(x[kj] * (cbf@Wcbf), ji)
    tsum_kernel<<<E_/4, 256, 0, stream>>>(off_ji, kj_s, cbf_s, xbuf, Wc_b, ts);
    // m += silu(ts @ Wup)
    mgemm<64,128,2,false,0,false><<<E_/128, 256, 0, stream>>>(ts, WuT_b, nullptr, nullptr, m, nullptr);
    // tmp = silu(m @ Wa) * (rbf @ Wr2)
    mgemm<128,128,0,true,64,false><<<E_/128, 256, 0, stream>>>(m, WaT_b, rbf, Wr2T_b, tmp, nullptr);
    // a = seg(tmp, dst)
    asum_kernel<<<N_*16/256, 256, 0, stream>>>(off_dst, list_dst, tmp, a);
    // h += silu(a @ Wh)
    mgemm<128,128,3,false,0,false><<<N_/128, 256, 0, stream>>>(a, WhT_b, nullptr, nullptr, hbf, h);
    // hs = h @ Ws ; ht = h @ Wt (one dispatch)
    mgemm_st<<<dim3(N_/128, 2), 256, 0, stream>>>(hbf, WstT_b, hsb, htb);
    // m += silu(hs[src] + ht[dst])
    scat_kernel<<<E_*16/256, 256, 0, stream>>>(ei, hsb, htb, m);
  }

  // ---- readout ----
  mgemm<128,128,0,false,0,true><<<N_/128, 256, 0, stream>>>(hbf, WoutT, nullptr, nullptr, hW, nullptr);
  zred_kernel<<<128, 128, 0, stream>>>(hW, numat, z);
  gemm_k<32,128,3,false><<<dim3(4,2), 256, 0, stream>>>(z,  Wfc0, 128, f0, 256, bfc0);
  gemm_k<32,128,3,false><<<dim3(4,2), 256, 0, stream>>>(f0, Wfc1, 256, f1, 256, bfc1);
  gemm_k<32,128,4,true ><<<dim3(4,2), 256, 0, stream>>>(f1, Wfc2, 256, out, 230, bfc2);
}

// Round 6
// 742.028 us; speedup vs baseline: 2.4603x; 1.1006x over previous
//
#include <hip/hip_runtime.h>
#include <hip/hip_bf16.h>
#include <math.h>

constexpr int B_ = 128, N_ = 4096, E_ = 65536, T_ = 262144;

typedef __attribute__((ext_vector_type(8))) __bf16 bf16x8;
typedef __attribute__((ext_vector_type(4))) float f32x4;
typedef __hip_bfloat16 bf16;

__device__ __forceinline__ float silu_f(float x){ return x / (1.0f + __expf(-x)); }
__device__ __forceinline__ float bf2f(bf16 v){ return __bfloat162float(v); }
__device__ __forceinline__ bf16  f2bf(float v){ return __float2bfloat16(v); }
__device__ __forceinline__ float bfx(bf16x8 v, int j){ __bf16 t = v[j]; return (float)t; }
__device__ __forceinline__ int   swz(int row, int col){ return col ^ ((row & 7) << 3); }

// ================= CSR build (fused) =================
__global__ void hist2_kernel(const int* __restrict__ ji, const int* __restrict__ eidst,
                             int* __restrict__ cnt_ji, int* __restrict__ cnt_dst){
  int i = blockIdx.x*256 + threadIdx.x;
  if(i < T_) atomicAdd(&cnt_ji[ji[i]], 1);
  else       atomicAdd(&cnt_dst[eidst[i - T_]], 1);
}
__global__ void fill2_kernel(const int* __restrict__ ji, const int* __restrict__ eidst,
                             int* __restrict__ cur_ji, int* __restrict__ list_ji,
                             int* __restrict__ cur_dst, int* __restrict__ list_dst){
  int i = blockIdx.x*256 + threadIdx.x;
  if(i < T_){ int p = atomicAdd(&cur_ji[ji[i]], 1); list_ji[p] = i; }
  else { int e = i - T_; int p = atomicAdd(&cur_dst[eidst[e]], 1); list_dst[p] = e; }
}
__global__ __launch_bounds__(1024) void scan2_kernel(const int* __restrict__ cj, int* __restrict__ oj, int* __restrict__ uj,
                                                     const int* __restrict__ cd, int* __restrict__ od, int* __restrict__ ud){
  __shared__ int sh[1024];
  const int* cnt; int* offs; int* cur; int per, n;
  if(blockIdx.x == 0){ cnt = cj; offs = oj; cur = uj; per = 64; n = E_; }
  else               { cnt = cd; offs = od; cur = ud; per = 4;  n = N_; }
  int t = threadIdx.x;
  int base = t * per;
  int s = 0;
  for(int i = 0; i < per; i++) s += cnt[base + i];
  sh[t] = s;
  __syncthreads();
  for(int d = 1; d < 1024; d <<= 1){
    int v = (t >= d) ? sh[t - d] : 0;
    __syncthreads();
    sh[t] += v;
    __syncthreads();
  }
  int run = sh[t] - s;
  for(int i = 0; i < per; i++){
    offs[base + i] = run; cur[base + i] = run;
    run += cnt[base + i];
  }
  if(t == 1023) offs[n] = run;
}

// ================= geometry =================
__global__ void pos_kernel(const float* __restrict__ frac, const float* __restrict__ lengths,
                           const float* __restrict__ angles, float* __restrict__ pos){
  int i = blockIdx.x*256 + threadIdx.x;
  if(i >= N_) return;
  int b = i >> 5;
  const float d2r = 0.017453292519943295f;
  float La = lengths[b*3+0], Lb = lengths[b*3+1], Lc = lengths[b*3+2];
  float al = angles[b*3+0]*d2r, be = angles[b*3+1]*d2r, ga = angles[b*3+2]*d2r;
  float ca = cosf(al), cb = cosf(be), cg = cosf(ga), sg = sinf(ga);
  float cx = cb, cy = (ca - cb*cg) / sg;
  float cz = sqrtf(fmaxf(1.0f - cx*cx - cy*cy, 1e-8f));
  float l00 = La, l10 = Lb*cg, l11 = Lb*sg, l20 = Lc*cx, l21 = Lc*cy, l22 = Lc*cz;
  float fx = frac[i*3], fy = frac[i*3+1], fz = frac[i*3+2];
  pos[i*3+0] = fx*l00 + fy*l10 + fz*l20;
  pos[i*3+1] = fy*l11 + fz*l21;
  pos[i*3+2] = fz*l22;
}

__global__ __launch_bounds__(256) void edge_kernel(const float* __restrict__ pos, const int* __restrict__ ei,
                                                   float* __restrict__ vec, bf16* __restrict__ rbf){
  int e = blockIdx.x*4 + (threadIdx.x >> 6);
  int lane = threadIdx.x & 63;
  int s = ei[e], d = ei[E_ + e];
  float vx = pos[d*3+0]-pos[s*3+0];
  float vy = pos[d*3+1]-pos[s*3+1];
  float vz = pos[d*3+2]-pos[s*3+2];
  float dd = sqrtf(vx*vx + vy*vy + vz*vz + 1e-12f);
  float dsc = dd * (1.0f/7.0f);
  float env = 0.0f;
  if(dsc < 1.0f){
    float d2 = dsc*dsc, d5 = d2*d2*dsc;
    env = 1.0f - 21.0f*d5 + 35.0f*d5*dsc - 15.0f*d5*d2;
  }
  float arg = (float)(lane+1) * 3.14159265358979f * dsc;
  rbf[(size_t)e*64 + lane] = f2bf(env * 0.5345224838248488f * sinf(arg) / dd);
  if(lane < 3){ vec[e*3+lane] = (lane==0) ? vx : (lane==1 ? vy : vz); }
}

// tprep: at sorted CSR position idx: kj_s, Chebyshev cbf_s (cos(s*acos x) = T_s(x))
__global__ __launch_bounds__(256) void tprep_kernel(const int* __restrict__ list, const int* __restrict__ ji,
                                                    const int* __restrict__ kj, const float* __restrict__ vec,
                                                    bf16* __restrict__ cbf_s, int* __restrict__ kj_s){
  int idx = blockIdx.x*256 + threadIdx.x;
  int t = list[idx];
  int a = ji[t], b = kj[t];
  kj_s[idx] = b;
  float ax = vec[a*3], ay = vec[a*3+1], az = vec[a*3+2];
  float bx = vec[b*3], by = vec[b*3+1], bz = vec[b*3+2];
  float dot = ax*bx + ay*by + az*bz;
  float na = sqrtf(ax*ax + ay*ay + az*az);
  float nb = sqrtf(bx*bx + by*by + bz*bz);
  float x = dot / (na*nb + 1e-9f);
  x = fminf(fmaxf(x, -1.0f + 1e-6f), 1.0f - 1e-6f);
  float c[16];
  c[0] = 1.0f; c[1] = x;
  float x2 = 2.0f * x;
  #pragma unroll
  for(int s = 2; s < 16; s++) c[s] = x2*c[s-1] - c[s-2];
  bf16x8 o0, o1;
  #pragma unroll
  for(int j = 0; j < 8; j++){ o0[j] = (__bf16)c[j]; o1[j] = (__bf16)c[8+j]; }
  *(bf16x8*)&cbf_s[(size_t)idx*16]     = o0;
  *(bf16x8*)&cbf_s[(size_t)idx*16 + 8] = o1;
}

// ================= weight transpose+convert =================
struct WDesc { const float* src; bf16* dst; int K; int shN; };
struct WPackAll { WDesc d[29]; };
__global__ __launch_bounds__(256) void wconv_kernel(WPackAll p){
  WDesc w = p.d[blockIdx.y];
  int idx = blockIdx.x*256 + threadIdx.x;
  int NN = 1 << w.shN;
  if(idx >= w.K * NN) return;
  int k = idx >> w.shN, c = idx & (NN - 1);
  w.dst[(size_t)c * w.K + k] = f2bf(w.src[idx]);
}

// ================= h init =================
__global__ __launch_bounds__(128) void h0_kernel(const float* __restrict__ emb, const int* __restrict__ types,
                                                 const float* __restrict__ noise, const float* __restrict__ Whz,
                                                 float* __restrict__ h, bf16* __restrict__ hbf){
  __shared__ float arow[129];
  int i = blockIdx.x;
  int c = threadIdx.x;
  arow[c] = emb[(size_t)types[i]*128 + c];
  if(c == 0) arow[128] = noise[i >> 5];
  __syncthreads();
  float acc = 0.f;
  for(int k = 0; k < 129; k++) acc += arow[k] * Whz[(size_t)k*128 + c];
  float v = silu_f(acc);
  h[(size_t)i*128 + c] = v;
  hbf[(size_t)i*128 + c] = f2bf(v);
}

// ================= MFMA cores =================
template<int KK, int FM>
__device__ __forceinline__ void kloop(const bf16* __restrict__ A, const bf16* __restrict__ W,
                                      int rowA0, int colW0, int lr, int lk, f32x4 (*acc)[4])
{
  #pragma unroll
  for(int k0 = 0; k0 < KK; k0 += 32){
    bf16x8 af[FM], bv[4];
    #pragma unroll
    for(int fm = 0; fm < FM; fm++)
      af[fm] = *(const bf16x8*)(A + (size_t)(rowA0 + fm*16 + lr)*KK + k0 + lk*8);
    #pragma unroll
    for(int fn = 0; fn < 4; fn++)
      bv[fn] = *(const bf16x8*)(W + (size_t)(colW0 + fn*16 + lr)*KK + k0 + lk*8);
    #pragma unroll
    for(int fm = 0; fm < FM; fm++)
      #pragma unroll
      for(int fn = 0; fn < 4; fn++)
        acc[fm][fn] = __builtin_amdgcn_mfma_f32_16x16x32_bf16(af[fm], bv[fn], acc[fm][fn], 0, 0, 0);
  }
}

// A from swizzled LDS tile [128 rows][128 cols], W from global [ncols][128]
template<int FM>
__device__ __forceinline__ void kloop_lds(const __bf16* sA, const bf16* __restrict__ W,
                                          int rowL0, int colW0, int lr, int lk, f32x4 (*acc)[4])
{
  #pragma unroll
  for(int k0 = 0; k0 < 128; k0 += 32){
    bf16x8 af[FM], bv[4];
    #pragma unroll
    for(int fm = 0; fm < FM; fm++){
      int row = rowL0 + fm*16 + lr;
      af[fm] = *(const bf16x8*)&sA[row*128 + swz(row, k0 + lk*8)];
    }
    #pragma unroll
    for(int fn = 0; fn < 4; fn++)
      bv[fn] = *(const bf16x8*)(W + (size_t)(colW0 + fn*16 + lr)*128 + k0 + lk*8);
    #pragma unroll
    for(int fm = 0; fm < FM; fm++)
      #pragma unroll
      for(int fn = 0; fn < 4; fn++)
        acc[fm][fn] = __builtin_amdgcn_mfma_f32_16x16x32_bf16(af[fm], bv[fn], acc[fm][fn], 0, 0, 0);
  }
}

// m0: m = silu(concat(h[src],h[dst],rbf) @ W_edge)
__global__ __launch_bounds__(256, 2) void mgemm_m0(
    const bf16* __restrict__ hb, const bf16* __restrict__ rbf, const int* __restrict__ ei,
    const bf16* __restrict__ Wt /*[128][320]*/, bf16* __restrict__ mout)
{
  const int tid = threadIdx.x;
  const int wid = tid >> 6, lane = tid & 63;
  const int wr = wid >> 1, wc = wid & 1;
  const int lr = lane & 15, lk = lane >> 4;
  const int e0 = blockIdx.x*128 + wr*64;

  int esrc[4], edst[4];
  #pragma unroll
  for(int fm = 0; fm < 4; fm++){
    int e = e0 + fm*16 + lr;
    esrc[fm] = ei[e]; edst[fm] = ei[E_ + e];
  }
  f32x4 acc[4][4];
  #pragma unroll
  for(int i = 0; i < 4; i++)
    #pragma unroll
    for(int j = 0; j < 4; j++) acc[i][j] = (f32x4){0.f,0.f,0.f,0.f};

  #pragma unroll
  for(int ks = 0; ks < 10; ks++){
    const int k0 = ks*32;
    bf16x8 af[4], bv[4];
    #pragma unroll
    for(int fm = 0; fm < 4; fm++){
      const bf16* p;
      if(k0 < 128)      p = hb + (size_t)esrc[fm]*128 + k0;
      else if(k0 < 256) p = hb + (size_t)edst[fm]*128 + (k0 - 128);
      else              p = rbf + (size_t)(e0 + fm*16 + lr)*64 + (k0 - 256);
      af[fm] = *(const bf16x8*)(p + lk*8);
    }
    #pragma unroll
    for(int fn = 0; fn < 4; fn++)
      bv[fn] = *(const bf16x8*)(Wt + (size_t)(wc*64 + fn*16 + lr)*320 + k0 + lk*8);
    #pragma unroll
    for(int fm = 0; fm < 4; fm++)
      #pragma unroll
      for(int fn = 0; fn < 4; fn++)
        acc[fm][fn] = __builtin_amdgcn_mfma_f32_16x16x32_bf16(af[fm], bv[fn], acc[fm][fn], 0, 0, 0);
  }
  #pragma unroll
  for(int fm = 0; fm < 4; fm++)
    #pragma unroll
    for(int fn = 0; fn < 4; fn++)
      #pragma unroll
      for(int r = 0; r < 4; r++){
        int row = e0 + fm*16 + lk*4 + r;
        int col = wc*64 + fn*16 + lr;
        mout[(size_t)row*128 + col] = f2bf(silu_f(acc[fm][fn][r]));
      }
}

// ===== dd_fused: [scat] + dual silu(m@Wm)*(rbf@Wr1) + @Wdown =====
template<bool SCAT>
__global__ __launch_bounds__(256, 2) void dd_fused(
    bf16* __restrict__ m, const bf16* __restrict__ Wm,
    const bf16* __restrict__ rbf, const bf16* __restrict__ Wr1,
    const bf16* __restrict__ Wd, bf16* __restrict__ xout,
    const int* __restrict__ ei, const bf16* __restrict__ hs, const bf16* __restrict__ ht)
{
  __shared__ __bf16 sM[128*128];
  __shared__ __bf16 sT[128*128];
  const int tid = threadIdx.x;
  const int wid = tid >> 6, lane = tid & 63;
  const int wr = wid >> 1, wc = wid & 1;
  const int lr = lane & 15, lk = lane >> 4;
  const int row0 = blockIdx.x*128;

  // stage m' = m (+ silu(hs[src]+ht[dst])) into swizzled LDS; write back if SCAT
  {
    int r = tid >> 1, c0 = (tid & 1)*64;
    int e = row0 + r;
    int s = 0, d = 0;
    if(SCAT){ s = ei[e]; d = ei[E_ + e]; }
    #pragma unroll
    for(int j = 0; j < 8; j++){
      int col = c0 + j*8;
      bf16x8 vm = *(const bf16x8*)&m[(size_t)e*128 + col];
      if(SCAT){
        bf16x8 va = *(const bf16x8*)&hs[(size_t)s*128 + col];
        bf16x8 vb = *(const bf16x8*)&ht[(size_t)d*128 + col];
        #pragma unroll
        for(int q = 0; q < 8; q++) vm[q] = (__bf16)(bfx(vm,q) + silu_f(bfx(va,q) + bfx(vb,q)));
        *(bf16x8*)&m[(size_t)e*128 + col] = vm;
      }
      *(bf16x8*)&sM[r*128 + swz(r, col)] = vm;
    }
  }
  __syncthreads();

  // GEMM1 dual: sv = silu(m'@Wm); acc = rbf@Wr1
  f32x4 acc[4][4];
  #pragma unroll
  for(int i = 0; i < 4; i++)
    #pragma unroll
    for(int j = 0; j < 4; j++) acc[i][j] = (f32x4){0.f,0.f,0.f,0.f};
  kloop_lds<4>(sM, Wm, wr*64, wc*64, lr, lk, acc);
  float sv[4][4][4];
  #pragma unroll
  for(int i = 0; i < 4; i++)
    #pragma unroll
    for(int j = 0; j < 4; j++){
      #pragma unroll
      for(int r = 0; r < 4; r++) sv[i][j][r] = silu_f(acc[i][j][r]);
      acc[i][j] = (f32x4){0.f,0.f,0.f,0.f};
    }
  kloop<64,4>(rbf, Wr1, row0 + wr*64, wc*64, lr, lk, acc);

  // tmp tile -> swizzled LDS
  #pragma unroll
  for(int fm = 0; fm < 4; fm++)
    #pragma unroll
    for(int fn = 0; fn < 4; fn++)
      #pragma unroll
      for(int r = 0; r < 4; r++){
        int row = wr*64 + fm*16 + lk*4 + r;
        int col = wc*64 + fn*16 + lr;
        sT[row*128 + swz(row, col)] = (__bf16)(sv[fm][fn][r] * acc[fm][fn][r]);
      }
  __syncthreads();

  // GEMM2: x = tmp @ Wdown  (wave wid owns 32 rows; 64 output cols)
  f32x4 a2[2][4];
  #pragma unroll
  for(int i = 0; i < 2; i++)
    #pragma unroll
    for(int j = 0; j < 4; j++) a2[i][j] = (f32x4){0.f,0.f,0.f,0.f};
  kloop_lds<2>(sT, Wd, wid*32, 0, lr, lk, a2);
  #pragma unroll
  for(int fm = 0; fm < 2; fm++)
    #pragma unroll
    for(int fn = 0; fn < 4; fn++)
      #pragma unroll
      for(int r = 0; r < 4; r++){
        int row = wid*32 + fm*16 + lk*4 + r;
        int col = fn*16 + lr;
        xout[(size_t)(row0 + row)*64 + col] = f2bf(a2[fm][fn][r]);
      }
}

// ===== wup_wa: m += silu(ts@Wup); tmp = silu(m@Wa)*(rbf@Wr2) =====
template<bool WRITEM>
__global__ __launch_bounds__(256, 2) void wup_wa(
    const bf16* __restrict__ ts, const bf16* __restrict__ Wu,
    bf16* __restrict__ m, const bf16* __restrict__ Wa,
    const bf16* __restrict__ rbf, const bf16* __restrict__ Wr2,
    bf16* __restrict__ tmp)
{
  __shared__ __bf16 sMr[128*128];
  __shared__ __bf16 sU[128*128];
  const int tid = threadIdx.x;
  const int wid = tid >> 6, lane = tid & 63;
  const int wr = wid >> 1, wc = wid & 1;
  const int lr = lane & 15, lk = lane >> 4;
  const int row0 = blockIdx.x*128;

  // stage old m rows (coalesced) into swizzled LDS
  {
    int r = tid >> 1, c0 = (tid & 1)*64;
    #pragma unroll
    for(int j = 0; j < 8; j++){
      int col = c0 + j*8;
      bf16x8 vm = *(const bf16x8*)&m[(size_t)(row0 + r)*128 + col];
      *(bf16x8*)&sMr[r*128 + swz(r, col)] = vm;
    }
  }
  __syncthreads();

  // GEMM1: ts @ Wup (K=64)
  f32x4 acc[4][4];
  #pragma unroll
  for(int i = 0; i < 4; i++)
    #pragma unroll
    for(int j = 0; j < 4; j++) acc[i][j] = (f32x4){0.f,0.f,0.f,0.f};
  kloop<64,4>(ts, Wu, row0 + wr*64, wc*64, lr, lk, acc);

  // u = m + silu(.); write global m (optional) + swizzled LDS
  #pragma unroll
  for(int fm = 0; fm < 4; fm++)
    #pragma unroll
    for(int fn = 0; fn < 4; fn++)
      #pragma unroll
      for(int r = 0; r < 4; r++){
        int row = wr*64 + fm*16 + lk*4 + r;
        int col = wc*64 + fn*16 + lr;
        float x = (float)sMr[row*128 + swz(row, col)] + silu_f(acc[fm][fn][r]);
        if(WRITEM) m[(size_t)(row0 + row)*128 + col] = f2bf(x);
        sU[row*128 + swz(row, col)] = (__bf16)x;
      }
  __syncthreads();

  // GEMM2 dual: sv = silu(u@Wa) [LDS], acc = rbf@Wr2
  #pragma unroll
  for(int i = 0; i < 4; i++)
    #pragma unroll
    for(int j = 0; j < 4; j++) acc[i][j] = (f32x4){0.f,0.f,0.f,0.f};
  kloop_lds<4>(sU, Wa, wr*64, wc*64, lr, lk, acc);
  float sv[4][4][4];
  #pragma unroll
  for(int i = 0; i < 4; i++)
    #pragma unroll
    for(int j = 0; j < 4; j++){
      #pragma unroll
      for(int r = 0; r < 4; r++) sv[i][j][r] = silu_f(acc[i][j][r]);
      acc[i][j] = (f32x4){0.f,0.f,0.f,0.f};
    }
  kloop<64,4>(rbf, Wr2, row0 + wr*64, wc*64, lr, lk, acc);
  #pragma unroll
  for(int fm = 0; fm < 4; fm++)
    #pragma unroll
    for(int fn = 0; fn < 4; fn++)
      #pragma unroll
      for(int r = 0; r < 4; r++){
        int row = wr*64 + fm*16 + lk*4 + r;
        int col = wc*64 + fn*16 + lr;
        tmp[(size_t)(row0 + row)*128 + col] = f2bf(sv[fm][fn][r] * acc[fm][fn][r]);
      }
}

// ===== atom_fused: h += silu(a@Wh); then hs/ht (or hW on last iter) =====
template<bool LAST>
__global__ __launch_bounds__(256, 2) void atom_fused(
    const bf16* __restrict__ a, const bf16* __restrict__ Wh,
    float* __restrict__ h,
    const bf16* __restrict__ Wst, bf16* __restrict__ hs, bf16* __restrict__ ht,
    const bf16* __restrict__ Wo, float* __restrict__ hW)
{
  __shared__ __bf16 sH[128*128];
  const int tid = threadIdx.x;
  const int wid = tid >> 6, lane = tid & 63;
  const int wr = wid >> 1, wc = wid & 1;
  const int lr = lane & 15, lk = lane >> 4;
  const int row0 = blockIdx.x*128;

  f32x4 acc[4][4];
  #pragma unroll
  for(int i = 0; i < 4; i++)
    #pragma unroll
    for(int j = 0; j < 4; j++) acc[i][j] = (f32x4){0.f,0.f,0.f,0.f};
  kloop<128,4>(a, Wh, row0 + wr*64, wc*64, lr, lk, acc);

  #pragma unroll
  for(int fm = 0; fm < 4; fm++)
    #pragma unroll
    for(int fn = 0; fn < 4; fn++)
      #pragma unroll
      for(int r = 0; r < 4; r++){
        int row = wr*64 + fm*16 + lk*4 + r;
        int col = wc*64 + fn*16 + lr;
        size_t off = (size_t)(row0 + row)*128 + col;
        float x = h[off] + silu_f(acc[fm][fn][r]);
        h[off] = x;
        sH[row*128 + swz(row, col)] = (__bf16)x;
      }
  __syncthreads();

  if(!LAST){
    // hs = h'@Ws
    #pragma unroll
    for(int i = 0; i < 4; i++)
      #pragma unroll
      for(int j = 0; j < 4; j++) acc[i][j] = (f32x4){0.f,0.f,0.f,0.f};
    kloop_lds<4>(sH, Wst, wr*64, wc*64, lr, lk, acc);
    #pragma unroll
    for(int fm = 0; fm < 4; fm++)
      #pragma unroll
      for(int fn = 0; fn < 4; fn++)
        #pragma unroll
        for(int r = 0; r < 4; r++){
          int row = wr*64 + fm*16 + lk*4 + r;
          int col = wc*64 + fn*16 + lr;
          hs[(size_t)(row0 + row)*128 + col] = f2bf(acc[fm][fn][r]);
        }
    // ht = h'@Wt
    #pragma unroll
    for(int i = 0; i < 4; i++)
      #pragma unroll
      for(int j = 0; j < 4; j++) acc[i][j] = (f32x4){0.f,0.f,0.f,0.f};
    kloop_lds<4>(sH, Wst + 128*128, wr*64, wc*64, lr, lk, acc);
    #pragma unroll
    for(int fm = 0; fm < 4; fm++)
      #pragma unroll
      for(int fn = 0; fn < 4; fn++)
        #pragma unroll
        for(int r = 0; r < 4; r++){
          int row = wr*64 + fm*16 + lk*4 + r;
          int col = wc*64 + fn*16 + lr;
          ht[(size_t)(row0 + row)*128 + col] = f2bf(acc[fm][fn][r]);
        }
  } else {
    // hW = h'@Wout (fp32)
    #pragma unroll
    for(int i = 0; i < 4; i++)
      #pragma unroll
      for(int j = 0; j < 4; j++) acc[i][j] = (f32x4){0.f,0.f,0.f,0.f};
    kloop_lds<4>(sH, Wo, wr*64, wc*64, lr, lk, acc);
    #pragma unroll
    for(int fm = 0; fm < 4; fm++)
      #pragma unroll
      for(int fn = 0; fn < 4; fn++)
        #pragma unroll
        for(int r = 0; r < 4; r++){
          int row = wr*64 + fm*16 + lk*4 + r;
          int col = wc*64 + fn*16 + lr;
          hW[(size_t)(row0 + row)*128 + col] = acc[fm][fn][r];
        }
  }
}

// ================= triplet segsum (sorted streams) =================
__global__ __launch_bounds__(256) void tsum_kernel(const int* __restrict__ offs, const int* __restrict__ kj_s,
                                                   const bf16* __restrict__ cbf_s, const bf16* __restrict__ x,
                                                   const float* __restrict__ Wc, bf16* __restrict__ ts){
  int e = blockIdx.x*4 + (threadIdx.x >> 6);
  int lane = threadIdx.x & 63;
  float wcv[16];
  #pragma unroll
  for(int s = 0; s < 16; s++) wcv[s] = Wc[s*64 + lane];
  float acc = 0.f;
  int b0 = offs[e], b1 = offs[e+1];
  for(int idx = b0; idx < b1; ++idx){
    int k = kj_s[idx];
    bf16x8 c0 = *(const bf16x8*)&cbf_s[(size_t)idx*16];
    bf16x8 c1 = *(const bf16x8*)&cbf_s[(size_t)idx*16 + 8];
    float cw = 0.f;
    #pragma unroll
    for(int j = 0; j < 8; j++) cw += bfx(c0,j)*wcv[j] + bfx(c1,j)*wcv[8+j];
    acc += bf2f(x[(size_t)k*64 + lane]) * cw;
  }
  ts[(size_t)e*64 + lane] = f2bf(acc);
}

// ================= edge->atom segsum =================
__global__ __launch_bounds__(256) void asum_kernel(const int* __restrict__ offs, const int* __restrict__ list,
                                                   const bf16* __restrict__ buf, bf16* __restrict__ a){
  int g = blockIdx.x*256 + threadIdx.x;
  int i = g >> 4, c8 = g & 15;
  float acc[8];
  #pragma unroll
  for(int j = 0; j < 8; j++) acc[j] = 0.f;
  int b0 = offs[i], b1 = offs[i+1];
  for(int idx = b0; idx < b1; ++idx){
    bf16x8 v = *(const bf16x8*)&buf[(size_t)list[idx]*128 + c8*8];
    #pragma unroll
    for(int j = 0; j < 8; j++) acc[j] += bfx(v,j);
  }
  bf16x8 o;
  #pragma unroll
  for(int j = 0; j < 8; j++) o[j] = (__bf16)acc[j];
  *(bf16x8*)&a[(size_t)i*128 + c8*8] = o;
}

// ================= fused readout MLP (zred + 3 layers) =================
__global__ __launch_bounds__(256) void mlp_kernel(const float* __restrict__ hW, const int* __restrict__ numat,
    const float* __restrict__ W0, const float* __restrict__ b0,
    const float* __restrict__ W1, const float* __restrict__ b1,
    const float* __restrict__ W2, const float* __restrict__ b2,
    float* __restrict__ out)
{
  __shared__ float zs[128], x0[256], x1[256];
  int b = blockIdx.x, t = threadIdx.x;
  if(t < 128){
    float s = 0.f;
    #pragma unroll 4
    for(int i = 0; i < 32; i++) s += hW[((size_t)(b*32 + i))*128 + t];
    zs[t] = s / (float)numat[b];
  }
  __syncthreads();
  {
    float acc = b0[t];
    for(int k = 0; k < 128; k++) acc += zs[k] * W0[(size_t)k*256 + t];
    x0[t] = fmaxf(acc, 0.f);
  }
  __syncthreads();
  {
    float acc = b1[t];
    for(int k = 0; k < 256; k++) acc += x0[k] * W1[(size_t)k*256 + t];
    x1[t] = fmaxf(acc, 0.f);
  }
  __syncthreads();
  if(t < 230){
    float acc = b2[t];
    for(int k = 0; k < 256; k++) acc += x1[k] * W2[(size_t)k*230 + t];
    out[(size_t)b*230 + t] = acc;
  }
}

extern "C" void kernel_launch(void* const* d_in, const int* in_sizes, int n_in,
                              void* d_out, int out_size, void* d_ws, size_t ws_size,
                              hipStream_t stream)
{
  const float* noise   = (const float*)d_in[0];
  const float* frac    = (const float*)d_in[1];
  const float* lengths = (const float*)d_in[2];
  const float* angles  = (const float*)d_in[3];
  const int*   types   = (const int*)d_in[4];
  const int*   numat   = (const int*)d_in[5];
  const int*   ei      = (const int*)d_in[6];
  const int*   ji      = (const int*)d_in[7];
  const int*   kj      = (const int*)d_in[8];
  const float* emb     = (const float*)d_in[9];
  const float* Whz     = (const float*)d_in[10];
  const float* Wedge   = (const float*)d_in[11];
  const float* Wm      = (const float*)d_in[12];
  const float* Wr1     = (const float*)d_in[13];
  const float* Wdown   = (const float*)d_in[14];
  const float* Wcbf    = (const float*)d_in[15];
  const float* Wup     = (const float*)d_in[16];
  const float* Wa      = (const float*)d_in[17];
  const float* Wr2     = (const float*)d_in[18];
  const float* Wh      = (const float*)d_in[19];
  const float* Wsw     = (const float*)d_in[20];
  const float* Wtw     = (const float*)d_in[21];
  const float* Wout    = (const float*)d_in[22];
  const float* Wfc0    = (const float*)d_in[23];
  const float* bfc0    = (const float*)d_in[24];
  const float* Wfc1    = (const float*)d_in[25];
  const float* bfc1    = (const float*)d_in[26];
  const float* Wfc2    = (const float*)d_in[27];
  const float* bfc2    = (const float*)d_in[28];
  float* out = (float*)d_out;

  char* base = (char*)d_ws;
  size_t oo = 0;
  auto ab = [&](size_t bytes)->void*{ void* p = base + oo; oo += bytes; oo = (oo + 63) & ~(size_t)63; return p; };

  float* pos   = (float*)ab((size_t)N_*3*4);
  float* vec   = (float*)ab((size_t)E_*3*4);
  bf16*  rbf   = (bf16*) ab((size_t)E_*64*2);
  bf16*  cbf_s = (bf16*) ab((size_t)T_*16*2);
  int*   kj_s  = (int*)  ab((size_t)T_*4);
  float* h     = (float*)ab((size_t)N_*128*4);
  bf16*  hbf   = (bf16*) ab((size_t)N_*128*2);
  bf16*  m     = (bf16*) ab((size_t)E_*128*2);
  bf16*  tmp   = (bf16*) ab((size_t)E_*128*2);
  bf16*  ts    = (bf16*) ab((size_t)E_*64*2);
  bf16*  xbuf  = (bf16*) ab((size_t)E_*64*2);
  bf16*  a     = (bf16*) ab((size_t)N_*128*2);
  bf16*  hsb   = (bf16*) ab((size_t)N_*128*2);
  bf16*  htb   = (bf16*) ab((size_t)N_*128*2);
  float* hW    = (float*)ab((size_t)N_*128*4);

  bf16* WedgeT = (bf16*)ab(320*128*2);
  bf16* WmT    = (bf16*)ab((size_t)3*128*128*2);
  bf16* Wr1T   = (bf16*)ab((size_t)3*128*64*2);
  bf16* WdownT = (bf16*)ab((size_t)3*64*128*2);
  bf16* WupT   = (bf16*)ab((size_t)3*128*64*2);
  bf16* WaT    = (bf16*)ab((size_t)3*128*128*2);
  bf16* Wr2T   = (bf16*)ab((size_t)3*128*64*2);
  bf16* WhT    = (bf16*)ab((size_t)3*128*128*2);
  bf16* WstT   = (bf16*)ab((size_t)3*2*128*128*2);
  bf16* WoutT  = (bf16*)ab(128*128*2);

  int* cnt_ji   = (int*)ab((size_t)(E_ + N_)*4);   // cnt_ji || cnt_dst adjacent (single memset)
  int* cnt_dst  = cnt_ji + E_;
  int* off_ji   = (int*)ab((size_t)(E_+1)*4);
  int* cur_ji   = (int*)ab((size_t)E_*4);
  int* list_ji  = (int*)ab((size_t)T_*4);
  int* off_dst  = (int*)ab((size_t)(N_+1)*4);
  int* cur_dst  = (int*)ab((size_t)N_*4);
  int* list_dst = (int*)ab((size_t)E_*4);

  // ---- weight conversion (single dispatch) ----
  WPackAll p{};
  {
    int i = 0;
    p.d[i++] = {Wedge, WedgeT, 320, 7};
    for(int b=0;b<3;b++) p.d[i++] = {Wm   + (size_t)b*128*128, WmT   + (size_t)b*128*128, 128, 7};
    for(int b=0;b<3;b++) p.d[i++] = {Wr1  + (size_t)b*64*128,  Wr1T  + (size_t)b*128*64,   64, 7};
    for(int b=0;b<3;b++) p.d[i++] = {Wdown+ (size_t)b*128*64,  WdownT+ (size_t)b*64*128,  128, 6};
    for(int b=0;b<3;b++) p.d[i++] = {Wup  + (size_t)b*64*128,  WupT  + (size_t)b*128*64,   64, 7};
    for(int b=0;b<3;b++) p.d[i++] = {Wa   + (size_t)b*128*128, WaT   + (size_t)b*128*128, 128, 7};
    for(int b=0;b<3;b++) p.d[i++] = {Wr2  + (size_t)b*64*128,  Wr2T  + (size_t)b*128*64,   64, 7};
    for(int b=0;b<3;b++) p.d[i++] = {Wh   + (size_t)b*128*128, WhT   + (size_t)b*128*128, 128, 7};
    for(int b=0;b<3;b++) p.d[i++] = {Wsw  + (size_t)b*128*128, WstT  + (size_t)b*2*128*128,            128, 7};
    for(int b=0;b<3;b++) p.d[i++] = {Wtw  + (size_t)b*128*128, WstT  + (size_t)b*2*128*128 + 128*128,  128, 7};
    p.d[i++] = {Wout, WoutT, 128, 7};
    wconv_kernel<<<dim3(160,29), 256, 0, stream>>>(p);
  }

  // ---- CSR builds (4 dispatches) ----
  hipMemsetAsync(cnt_ji, 0, (size_t)(E_ + N_)*sizeof(int), stream);
  hist2_kernel<<<(T_+E_)/256, 256, 0, stream>>>(ji, ei + E_, cnt_ji, cnt_dst);
  scan2_kernel<<<2, 1024, 0, stream>>>(cnt_ji, off_ji, cur_ji, cnt_dst, off_dst, cur_dst);
  fill2_kernel<<<(T_+E_)/256, 256, 0, stream>>>(ji, ei + E_, cur_ji, list_ji, cur_dst, list_dst);

  // ---- geometry + init ----
  pos_kernel<<<N_/256, 256, 0, stream>>>(frac, lengths, angles, pos);
  edge_kernel<<<E_/4, 256, 0, stream>>>(pos, ei, vec, rbf);
  tprep_kernel<<<T_/256, 256, 0, stream>>>(list_ji, ji, kj, vec, cbf_s, kj_s);
  h0_kernel<<<N_, 128, 0, stream>>>(emb, types, noise, Whz, h, hbf);
  mgemm_m0<<<E_/128, 256, 0, stream>>>(hbf, rbf, ei, WedgeT, m);

  for(int b = 0; b < 3; b++){
    const bf16* WmT_b  = WmT   + (size_t)b*128*128;
    const bf16* Wr1T_b = Wr1T  + (size_t)b*128*64;
    const bf16* WdT_b  = WdownT+ (size_t)b*64*128;
    const float* Wc_b  = Wcbf  + (size_t)b*16*64;
    const bf16* WuT_b  = WupT  + (size_t)b*128*64;
    const bf16* WaT_b  = WaT   + (size_t)b*128*128;
    const bf16* Wr2T_b = Wr2T  + (size_t)b*128*64;
    const bf16* WhT_b  = WhT   + (size_t)b*128*128;
    const bf16* WstT_b = WstT  + (size_t)b*2*128*128;

    // [scat of prev iter] + x = (silu(m@Wm)*(rbf@Wr1)) @ Wdown
    if(b == 0) dd_fused<false><<<E_/128, 256, 0, stream>>>(m, WmT_b, rbf, Wr1T_b, WdT_b, xbuf, ei, hsb, htb);
    else       dd_fused<true ><<<E_/128, 256, 0, stream>>>(m, WmT_b, rbf, Wr1T_b, WdT_b, xbuf, ei, hsb, htb);
    // ts = seg(x[kj] * (cbf@Wcbf), ji)
    tsum_kernel<<<E_/4, 256, 0, stream>>>(off_ji, kj_s, cbf_s, xbuf, Wc_b, ts);
    // m += silu(ts@Wup); tmp = silu(m@Wa)*(rbf@Wr2)
    if(b < 2) wup_wa<true ><<<E_/128, 256, 0, stream>>>(ts, WuT_b, m, WaT_b, rbf, Wr2T_b, tmp);
    else      wup_wa<false><<<E_/128, 256, 0, stream>>>(ts, WuT_b, m, WaT_b, rbf, Wr2T_b, tmp);
    // a = seg(tmp, dst)
    asum_kernel<<<N_*16/256, 256, 0, stream>>>(off_dst, list_dst, tmp, a);
    // h += silu(a@Wh); hs/ht (or hW on last iter)
    if(b < 2) atom_fused<false><<<N_/128, 256, 0, stream>>>(a, WhT_b, h, WstT_b, hsb, htb, WoutT, hW);
    else      atom_fused<true ><<<N_/128, 256, 0, stream>>>(a, WhT_b, h, WstT_b, hsb, htb, WoutT, hW);
  }

  // ---- fused readout ----
  mlp_kernel<<<B_, 256, 0, stream>>>(hW, numat, Wfc0, bfc0, Wfc1, bfc1, Wfc2, bfc2, out);
}

// Round 7
// 608.906 us; speedup vs baseline: 2.9982x; 1.2186x over previous
//
#include <hip/hip_runtime.h>
#include <hip/hip_bf16.h>
#include <math.h>

constexpr int B_ = 128, N_ = 4096, E_ = 65536, T_ = 262144;

typedef __attribute__((ext_vector_type(8))) __bf16 bf16x8;
typedef __attribute__((ext_vector_type(4))) float f32x4;
typedef __hip_bfloat16 bf16;

__device__ __forceinline__ float silu_f(float x){ return x / (1.0f + __expf(-x)); }
__device__ __forceinline__ float bf2f(bf16 v){ return __bfloat162float(v); }
__device__ __forceinline__ bf16  f2bf(float v){ return __float2bfloat16(v); }
__device__ __forceinline__ float bfx(bf16x8 v, int j){ __bf16 t = v[j]; return (float)t; }
__device__ __forceinline__ int   swz(int row, int col){ return col ^ ((row & 7) << 3); }

// ================= CSR build =================
__global__ void hist2_kernel(const int* __restrict__ ji, const int* __restrict__ eidst,
                             int* __restrict__ cnt_ji, int* __restrict__ cnt_dst){
  int i = blockIdx.x*256 + threadIdx.x;
  if(i < T_) atomicAdd(&cnt_ji[ji[i]], 1);
  else       atomicAdd(&cnt_dst[eidst[i - T_]], 1);
}
__global__ void fill2_kernel(const int* __restrict__ ji, const int* __restrict__ eidst,
                             int* __restrict__ cur_ji, int* __restrict__ list_ji,
                             int* __restrict__ cur_dst, int* __restrict__ list_dst){
  int i = blockIdx.x*256 + threadIdx.x;
  if(i < T_){ int p = atomicAdd(&cur_ji[ji[i]], 1); list_ji[p] = i; }
  else { int e = i - T_; int p = atomicAdd(&cur_dst[eidst[e]], 1); list_dst[p] = e; }
}

// hierarchical scan: A = per-1024-chunk sums, B = scan chunk sums, C = apply.
// chunks: blocks 0..63 -> cnt_ji (E_=64K), blocks 64..67 -> cnt_dst (N_=4K)
__global__ __launch_bounds__(256) void scanA_kernel(const int* __restrict__ cnt_ji, const int* __restrict__ cnt_dst,
                                                    int* __restrict__ bsum){
  int blk = blockIdx.x;
  const int* src = (blk < 64) ? cnt_ji : cnt_dst;
  int base = (blk < 64) ? blk*1024 : (blk - 64)*1024;
  int t = threadIdx.x;
  int4 v = *(const int4*)&src[base + t*4];
  int s = v.x + v.y + v.z + v.w;
  #pragma unroll
  for(int d = 1; d < 64; d <<= 1) s += __shfl_xor(s, d);
  __shared__ int ws[4];
  if((t & 63) == 0) ws[t >> 6] = s;
  __syncthreads();
  if(t == 0) bsum[blk] = ws[0] + ws[1] + ws[2] + ws[3];
}
__global__ __launch_bounds__(128) void scanB_kernel(const int* __restrict__ bsum, int* __restrict__ boff){
  __shared__ int sh[68];
  int t = threadIdx.x;
  if(t < 68) sh[t] = bsum[t];
  __syncthreads();
  if(t == 0){
    int run = 0;
    for(int i = 0; i < 64; i++){ boff[i] = run; run += sh[i]; }
    run = 0;
    for(int i = 64; i < 68; i++){ boff[i] = run; run += sh[i]; }
  }
}
__global__ __launch_bounds__(256) void scanC_kernel(const int* __restrict__ cnt_ji, const int* __restrict__ cnt_dst,
                                                    const int* __restrict__ boff,
                                                    int* __restrict__ off_ji, int* __restrict__ cur_ji,
                                                    int* __restrict__ off_dst, int* __restrict__ cur_dst){
  int blk = blockIdx.x;
  const int* src; int* offs; int* cur; int base;
  if(blk < 64){ src = cnt_ji; offs = off_ji; cur = cur_ji; base = blk*1024; }
  else        { src = cnt_dst; offs = off_dst; cur = cur_dst; base = (blk - 64)*1024; }
  int t = threadIdx.x, lane = t & 63, w = t >> 6;
  int4 v = *(const int4*)&src[base + t*4];
  int s4 = v.x + v.y + v.z + v.w;
  int x = s4;
  #pragma unroll
  for(int d = 1; d < 64; d <<= 1){ int u = __shfl_up(x, d); if(lane >= d) x += u; }
  __shared__ int ws[4];
  if(lane == 63) ws[w] = x;
  __syncthreads();
  int wo = 0;
  for(int i = 0; i < w; i++) wo += ws[i];
  int o0 = boff[blk] + wo + (x - s4);   // exclusive prefix of this thread's first element
  int4 oo;
  oo.x = o0; oo.y = o0 + v.x; oo.z = oo.y + v.y; oo.w = oo.z + v.z;
  *(int4*)&offs[base + t*4] = oo;
  *(int4*)&cur[base + t*4]  = oo;
  if(blk == 0 && t == 0){ off_ji[E_] = T_; off_dst[N_] = E_; }  // totals are structural constants
}

// ================= geometry =================
__global__ void pos_kernel(const float* __restrict__ frac, const float* __restrict__ lengths,
                           const float* __restrict__ angles, float* __restrict__ pos){
  int i = blockIdx.x*256 + threadIdx.x;
  if(i >= N_) return;
  int b = i >> 5;
  const float d2r = 0.017453292519943295f;
  float La = lengths[b*3+0], Lb = lengths[b*3+1], Lc = lengths[b*3+2];
  float al = angles[b*3+0]*d2r, be = angles[b*3+1]*d2r, ga = angles[b*3+2]*d2r;
  float ca = cosf(al), cb = cosf(be), cg = cosf(ga), sg = sinf(ga);
  float cx = cb, cy = (ca - cb*cg) / sg;
  float cz = sqrtf(fmaxf(1.0f - cx*cx - cy*cy, 1e-8f));
  float l00 = La, l10 = Lb*cg, l11 = Lb*sg, l20 = Lc*cx, l21 = Lc*cy, l22 = Lc*cz;
  float fx = frac[i*3], fy = frac[i*3+1], fz = frac[i*3+2];
  pos[i*3+0] = fx*l00 + fy*l10 + fz*l20;
  pos[i*3+1] = fy*l11 + fz*l21;
  pos[i*3+2] = fz*l22;
}

__global__ __launch_bounds__(256) void edge_kernel(const float* __restrict__ pos, const int* __restrict__ ei,
                                                   float* __restrict__ vec, bf16* __restrict__ rbf){
  int e = blockIdx.x*4 + (threadIdx.x >> 6);
  int lane = threadIdx.x & 63;
  int s = ei[e], d = ei[E_ + e];
  float vx = pos[d*3+0]-pos[s*3+0];
  float vy = pos[d*3+1]-pos[s*3+1];
  float vz = pos[d*3+2]-pos[s*3+2];
  float dd = sqrtf(vx*vx + vy*vy + vz*vz + 1e-12f);
  float dsc = dd * (1.0f/7.0f);
  float env = 0.0f;
  if(dsc < 1.0f){
    float d2 = dsc*dsc, d5 = d2*d2*dsc;
    env = 1.0f - 21.0f*d5 + 35.0f*d5*dsc - 15.0f*d5*d2;
  }
  float arg = (float)(lane+1) * 3.14159265358979f * dsc;
  rbf[(size_t)e*64 + lane] = f2bf(env * 0.5345224838248488f * sinf(arg) / dd);
  if(lane < 3){ vec[e*3+lane] = (lane==0) ? vx : (lane==1 ? vy : vz); }
}

// tprep: at sorted CSR position idx: kj_s, Chebyshev cbf_s (cos(s*acos x) = T_s(x))
__global__ __launch_bounds__(256) void tprep_kernel(const int* __restrict__ list, const int* __restrict__ ji,
                                                    const int* __restrict__ kj, const float* __restrict__ vec,
                                                    bf16* __restrict__ cbf_s, int* __restrict__ kj_s){
  int idx = blockIdx.x*256 + threadIdx.x;
  int t = list[idx];
  int a = ji[t], b = kj[t];
  kj_s[idx] = b;
  float ax = vec[a*3], ay = vec[a*3+1], az = vec[a*3+2];
  float bx = vec[b*3], by = vec[b*3+1], bz = vec[b*3+2];
  float dot = ax*bx + ay*by + az*bz;
  float na = sqrtf(ax*ax + ay*ay + az*az);
  float nb = sqrtf(bx*bx + by*by + bz*bz);
  float x = dot / (na*nb + 1e-9f);
  x = fminf(fmaxf(x, -1.0f + 1e-6f), 1.0f - 1e-6f);
  float c[16];
  c[0] = 1.0f; c[1] = x;
  float x2 = 2.0f * x;
  #pragma unroll
  for(int s = 2; s < 16; s++) c[s] = x2*c[s-1] - c[s-2];
  bf16x8 o0, o1;
  #pragma unroll
  for(int j = 0; j < 8; j++){ o0[j] = (__bf16)c[j]; o1[j] = (__bf16)c[8+j]; }
  *(bf16x8*)&cbf_s[(size_t)idx*16]     = o0;
  *(bf16x8*)&cbf_s[(size_t)idx*16 + 8] = o1;
}

// ================= weight transpose+convert =================
struct WDesc { const float* src; bf16* dst; int K; int shN; };
struct WPackAll { WDesc d[29]; };
__global__ __launch_bounds__(256) void wconv_kernel(WPackAll p){
  WDesc w = p.d[blockIdx.y];
  int idx = blockIdx.x*256 + threadIdx.x;
  int NN = 1 << w.shN;
  if(idx >= w.K * NN) return;
  int k = idx >> w.shN, c = idx & (NN - 1);
  w.dst[(size_t)c * w.K + k] = f2bf(w.src[idx]);
}

// ================= h init =================
__global__ __launch_bounds__(128) void h0_kernel(const float* __restrict__ emb, const int* __restrict__ types,
                                                 const float* __restrict__ noise, const float* __restrict__ Whz,
                                                 float* __restrict__ h, bf16* __restrict__ hbf){
  __shared__ float arow[129];
  int i = blockIdx.x;
  int c = threadIdx.x;
  arow[c] = emb[(size_t)types[i]*128 + c];
  if(c == 0) arow[128] = noise[i >> 5];
  __syncthreads();
  float acc = 0.f;
  for(int k = 0; k < 129; k++) acc += arow[k] * Whz[(size_t)k*128 + c];
  float v = silu_f(acc);
  h[(size_t)i*128 + c] = v;
  hbf[(size_t)i*128 + c] = f2bf(v);
}

// ================= MFMA cores =================
template<int KK, int FM>
__device__ __forceinline__ void kloop(const bf16* __restrict__ A, const bf16* __restrict__ W,
                                      int rowA0, int colW0, int lr, int lk, f32x4 (*acc)[4])
{
  #pragma unroll
  for(int k0 = 0; k0 < KK; k0 += 32){
    bf16x8 af[FM], bv[4];
    #pragma unroll
    for(int fm = 0; fm < FM; fm++)
      af[fm] = *(const bf16x8*)(A + (size_t)(rowA0 + fm*16 + lr)*KK + k0 + lk*8);
    #pragma unroll
    for(int fn = 0; fn < 4; fn++)
      bv[fn] = *(const bf16x8*)(W + (size_t)(colW0 + fn*16 + lr)*KK + k0 + lk*8);
    #pragma unroll
    for(int fm = 0; fm < FM; fm++)
      #pragma unroll
      for(int fn = 0; fn < 4; fn++)
        acc[fm][fn] = __builtin_amdgcn_mfma_f32_16x16x32_bf16(af[fm], bv[fn], acc[fm][fn], 0, 0, 0);
  }
}

// A from swizzled LDS tile [128 rows][128 cols], W from global [ncols][128]
template<int FM>
__device__ __forceinline__ void kloop_lds(const __bf16* sA, const bf16* __restrict__ W,
                                          int rowL0, int colW0, int lr, int lk, f32x4 (*acc)[4])
{
  #pragma unroll
  for(int k0 = 0; k0 < 128; k0 += 32){
    bf16x8 af[FM], bv[4];
    #pragma unroll
    for(int fm = 0; fm < FM; fm++){
      int row = rowL0 + fm*16 + lr;
      af[fm] = *(const bf16x8*)&sA[row*128 + swz(row, k0 + lk*8)];
    }
    #pragma unroll
    for(int fn = 0; fn < 4; fn++)
      bv[fn] = *(const bf16x8*)(W + (size_t)(colW0 + fn*16 + lr)*128 + k0 + lk*8);
    #pragma unroll
    for(int fm = 0; fm < FM; fm++)
      #pragma unroll
      for(int fn = 0; fn < 4; fn++)
        acc[fm][fn] = __builtin_amdgcn_mfma_f32_16x16x32_bf16(af[fm], bv[fn], acc[fm][fn], 0, 0, 0);
  }
}

// m0: m = silu(concat(h[src],h[dst],rbf) @ W_edge)
__global__ __launch_bounds__(256, 2) void mgemm_m0(
    const bf16* __restrict__ hb, const bf16* __restrict__ rbf, const int* __restrict__ ei,
    const bf16* __restrict__ Wt /*[128][320]*/, bf16* __restrict__ mout)
{
  const int tid = threadIdx.x;
  const int wid = tid >> 6, lane = tid & 63;
  const int wr = wid >> 1, wc = wid & 1;
  const int lr = lane & 15, lk = lane >> 4;
  const int e0 = blockIdx.x*128 + wr*64;

  int esrc[4], edst[4];
  #pragma unroll
  for(int fm = 0; fm < 4; fm++){
    int e = e0 + fm*16 + lr;
    esrc[fm] = ei[e]; edst[fm] = ei[E_ + e];
  }
  f32x4 acc[4][4];
  #pragma unroll
  for(int i = 0; i < 4; i++)
    #pragma unroll
    for(int j = 0; j < 4; j++) acc[i][j] = (f32x4){0.f,0.f,0.f,0.f};

  #pragma unroll
  for(int ks = 0; ks < 10; ks++){
    const int k0 = ks*32;
    bf16x8 af[4], bv[4];
    #pragma unroll
    for(int fm = 0; fm < 4; fm++){
      const bf16* p;
      if(k0 < 128)      p = hb + (size_t)esrc[fm]*128 + k0;
      else if(k0 < 256) p = hb + (size_t)edst[fm]*128 + (k0 - 128);
      else              p = rbf + (size_t)(e0 + fm*16 + lr)*64 + (k0 - 256);
      af[fm] = *(const bf16x8*)(p + lk*8);
    }
    #pragma unroll
    for(int fn = 0; fn < 4; fn++)
      bv[fn] = *(const bf16x8*)(Wt + (size_t)(wc*64 + fn*16 + lr)*320 + k0 + lk*8);
    #pragma unroll
    for(int fm = 0; fm < 4; fm++)
      #pragma unroll
      for(int fn = 0; fn < 4; fn++)
        acc[fm][fn] = __builtin_amdgcn_mfma_f32_16x16x32_bf16(af[fm], bv[fn], acc[fm][fn], 0, 0, 0);
  }
  #pragma unroll
  for(int fm = 0; fm < 4; fm++)
    #pragma unroll
    for(int fn = 0; fn < 4; fn++)
      #pragma unroll
      for(int r = 0; r < 4; r++){
        int row = e0 + fm*16 + lk*4 + r;
        int col = wc*64 + fn*16 + lr;
        mout[(size_t)row*128 + col] = f2bf(silu_f(acc[fm][fn][r]));
      }
}

// ===== dd_fused: [scat] + dual silu(m@Wm)*(rbf@Wr1) + @Wdown =====
template<bool SCAT>
__global__ __launch_bounds__(256, 2) void dd_fused(
    bf16* __restrict__ m, const bf16* __restrict__ Wm,
    const bf16* __restrict__ rbf, const bf16* __restrict__ Wr1,
    const bf16* __restrict__ Wd, bf16* __restrict__ xout,
    const int* __restrict__ ei, const bf16* __restrict__ hs, const bf16* __restrict__ ht)
{
  __shared__ __bf16 sM[128*128];
  __shared__ __bf16 sT[128*128];
  const int tid = threadIdx.x;
  const int wid = tid >> 6, lane = tid & 63;
  const int wr = wid >> 1, wc = wid & 1;
  const int lr = lane & 15, lk = lane >> 4;
  const int row0 = blockIdx.x*128;

  // stage m' = m (+ silu(hs[src]+ht[dst])) into swizzled LDS; write back if SCAT
  {
    int r = tid >> 1, c0 = (tid & 1)*64;
    int e = row0 + r;
    int s = 0, d = 0;
    if(SCAT){ s = ei[e]; d = ei[E_ + e]; }
    #pragma unroll
    for(int j = 0; j < 8; j++){
      int col = c0 + j*8;
      bf16x8 vm = *(const bf16x8*)&m[(size_t)e*128 + col];
      if(SCAT){
        bf16x8 va = *(const bf16x8*)&hs[(size_t)s*128 + col];
        bf16x8 vb = *(const bf16x8*)&ht[(size_t)d*128 + col];
        #pragma unroll
        for(int q = 0; q < 8; q++) vm[q] = (__bf16)(bfx(vm,q) + silu_f(bfx(va,q) + bfx(vb,q)));
        *(bf16x8*)&m[(size_t)e*128 + col] = vm;
      }
      *(bf16x8*)&sM[r*128 + swz(r, col)] = vm;
    }
  }
  __syncthreads();

  // GEMM1 dual: sv = silu(m'@Wm); acc = rbf@Wr1
  f32x4 acc[4][4];
  #pragma unroll
  for(int i = 0; i < 4; i++)
    #pragma unroll
    for(int j = 0; j < 4; j++) acc[i][j] = (f32x4){0.f,0.f,0.f,0.f};
  kloop_lds<4>(sM, Wm, wr*64, wc*64, lr, lk, acc);
  float sv[4][4][4];
  #pragma unroll
  for(int i = 0; i < 4; i++)
    #pragma unroll
    for(int j = 0; j < 4; j++){
      #pragma unroll
      for(int r = 0; r < 4; r++) sv[i][j][r] = silu_f(acc[i][j][r]);
      acc[i][j] = (f32x4){0.f,0.f,0.f,0.f};
    }
  kloop<64,4>(rbf, Wr1, row0 + wr*64, wc*64, lr, lk, acc);

  // tmp tile -> swizzled LDS
  #pragma unroll
  for(int fm = 0; fm < 4; fm++)
    #pragma unroll
    for(int fn = 0; fn < 4; fn++)
      #pragma unroll
      for(int r = 0; r < 4; r++){
        int row = wr*64 + fm*16 + lk*4 + r;
        int col = wc*64 + fn*16 + lr;
        sT[row*128 + swz(row, col)] = (__bf16)(sv[fm][fn][r] * acc[fm][fn][r]);
      }
  __syncthreads();

  // GEMM2: x = tmp @ Wdown  (wave wid owns 32 rows; 64 output cols)
  f32x4 a2[2][4];
  #pragma unroll
  for(int i = 0; i < 2; i++)
    #pragma unroll
    for(int j = 0; j < 4; j++) a2[i][j] = (f32x4){0.f,0.f,0.f,0.f};
  kloop_lds<2>(sT, Wd, wid*32, 0, lr, lk, a2);
  #pragma unroll
  for(int fm = 0; fm < 2; fm++)
    #pragma unroll
    for(int fn = 0; fn < 4; fn++)
      #pragma unroll
      for(int r = 0; r < 4; r++){
        int row = wid*32 + fm*16 + lk*4 + r;
        int col = fn*16 + lr;
        xout[(size_t)(row0 + row)*64 + col] = f2bf(a2[fm][fn][r]);
      }
}

// ===== wup_wa: m += silu(ts@Wup); tmp = silu(m@Wa)*(rbf@Wr2) =====
template<bool WRITEM>
__global__ __launch_bounds__(256, 2) void wup_wa(
    const bf16* __restrict__ ts, const bf16* __restrict__ Wu,
    bf16* __restrict__ m, const bf16* __restrict__ Wa,
    const bf16* __restrict__ rbf, const bf16* __restrict__ Wr2,
    bf16* __restrict__ tmp)
{
  __shared__ __bf16 sMr[128*128];
  __shared__ __bf16 sU[128*128];
  const int tid = threadIdx.x;
  const int wid = tid >> 6, lane = tid & 63;
  const int wr = wid >> 1, wc = wid & 1;
  const int lr = lane & 15, lk = lane >> 4;
  const int row0 = blockIdx.x*128;

  // stage old m rows (coalesced) into swizzled LDS
  {
    int r = tid >> 1, c0 = (tid & 1)*64;
    #pragma unroll
    for(int j = 0; j < 8; j++){
      int col = c0 + j*8;
      bf16x8 vm = *(const bf16x8*)&m[(size_t)(row0 + r)*128 + col];
      *(bf16x8*)&sMr[r*128 + swz(r, col)] = vm;
    }
  }
  __syncthreads();

  // GEMM1: ts @ Wup (K=64)
  f32x4 acc[4][4];
  #pragma unroll
  for(int i = 0; i < 4; i++)
    #pragma unroll
    for(int j = 0; j < 4; j++) acc[i][j] = (f32x4){0.f,0.f,0.f,0.f};
  kloop<64,4>(ts, Wu, row0 + wr*64, wc*64, lr, lk, acc);

  // u = m + silu(.); write global m (optional) + swizzled LDS
  #pragma unroll
  for(int fm = 0; fm < 4; fm++)
    #pragma unroll
    for(int fn = 0; fn < 4; fn++)
      #pragma unroll
      for(int r = 0; r < 4; r++){
        int row = wr*64 + fm*16 + lk*4 + r;
        int col = wc*64 + fn*16 + lr;
        float x = (float)sMr[row*128 + swz(row, col)] + silu_f(acc[fm][fn][r]);
        if(WRITEM) m[(size_t)(row0 + row)*128 + col] = f2bf(x);
        sU[row*128 + swz(row, col)] = (__bf16)x;
      }
  __syncthreads();

  // GEMM2 dual: sv = silu(u@Wa) [LDS], acc = rbf@Wr2
  #pragma unroll
  for(int i = 0; i < 4; i++)
    #pragma unroll
    for(int j = 0; j < 4; j++) acc[i][j] = (f32x4){0.f,0.f,0.f,0.f};
  kloop_lds<4>(sU, Wa, wr*64, wc*64, lr, lk, acc);
  float sv[4][4][4];
  #pragma unroll
  for(int i = 0; i < 4; i++)
    #pragma unroll
    for(int j = 0; j < 4; j++){
      #pragma unroll
      for(int r = 0; r < 4; r++) sv[i][j][r] = silu_f(acc[i][j][r]);
      acc[i][j] = (f32x4){0.f,0.f,0.f,0.f};
    }
  kloop<64,4>(rbf, Wr2, row0 + wr*64, wc*64, lr, lk, acc);
  #pragma unroll
  for(int fm = 0; fm < 4; fm++)
    #pragma unroll
    for(int fn = 0; fn < 4; fn++)
      #pragma unroll
      for(int r = 0; r < 4; r++){
        int row = wr*64 + fm*16 + lk*4 + r;
        int col = wc*64 + fn*16 + lr;
        tmp[(size_t)(row0 + row)*128 + col] = f2bf(sv[fm][fn][r] * acc[fm][fn][r]);
      }
}

// ===== atom_fused: h += silu(a@Wh); then hs/ht (or hW on last iter) =====
template<bool LAST>
__global__ __launch_bounds__(256, 2) void atom_fused(
    const bf16* __restrict__ a, const bf16* __restrict__ Wh,
    float* __restrict__ h,
    const bf16* __restrict__ Wst, bf16* __restrict__ hs, bf16* __restrict__ ht,
    const bf16* __restrict__ Wo, float* __restrict__ hW)
{
  __shared__ __bf16 sH[128*128];
  const int tid = threadIdx.x;
  const int wid = tid >> 6, lane = tid & 63;
  const int wr = wid >> 1, wc = wid & 1;
  const int lr = lane & 15, lk = lane >> 4;
  const int row0 = blockIdx.x*128;

  f32x4 acc[4][4];
  #pragma unroll
  for(int i = 0; i < 4; i++)
    #pragma unroll
    for(int j = 0; j < 4; j++) acc[i][j] = (f32x4){0.f,0.f,0.f,0.f};
  kloop<128,4>(a, Wh, row0 + wr*64, wc*64, lr, lk, acc);

  #pragma unroll
  for(int fm = 0; fm < 4; fm++)
    #pragma unroll
    for(int fn = 0; fn < 4; fn++)
      #pragma unroll
      for(int r = 0; r < 4; r++){
        int row = wr*64 + fm*16 + lk*4 + r;
        int col = wc*64 + fn*16 + lr;
        size_t off = (size_t)(row0 + row)*128 + col;
        float x = h[off] + silu_f(acc[fm][fn][r]);
        h[off] = x;
        sH[row*128 + swz(row, col)] = (__bf16)x;
      }
  __syncthreads();

  if(!LAST){
    // hs = h'@Ws
    #pragma unroll
    for(int i = 0; i < 4; i++)
      #pragma unroll
      for(int j = 0; j < 4; j++) acc[i][j] = (f32x4){0.f,0.f,0.f,0.f};
    kloop_lds<4>(sH, Wst, wr*64, wc*64, lr, lk, acc);
    #pragma unroll
    for(int fm = 0; fm < 4; fm++)
      #pragma unroll
      for(int fn = 0; fn < 4; fn++)
        #pragma unroll
        for(int r = 0; r < 4; r++){
          int row = wr*64 + fm*16 + lk*4 + r;
          int col = wc*64 + fn*16 + lr;
          hs[(size_t)(row0 + row)*128 + col] = f2bf(acc[fm][fn][r]);
        }
    // ht = h'@Wt
    #pragma unroll
    for(int i = 0; i < 4; i++)
      #pragma unroll
      for(int j = 0; j < 4; j++) acc[i][j] = (f32x4){0.f,0.f,0.f,0.f};
    kloop_lds<4>(sH, Wst + 128*128, wr*64, wc*64, lr, lk, acc);
    #pragma unroll
    for(int fm = 0; fm < 4; fm++)
      #pragma unroll
      for(int fn = 0; fn < 4; fn++)
        #pragma unroll
        for(int r = 0; r < 4; r++){
          int row = wr*64 + fm*16 + lk*4 + r;
          int col = wc*64 + fn*16 + lr;
          ht[(size_t)(row0 + row)*128 + col] = f2bf(acc[fm][fn][r]);
        }
  } else {
    // hW = h'@Wout (fp32)
    #pragma unroll
    for(int i = 0; i < 4; i++)
      #pragma unroll
      for(int j = 0; j < 4; j++) acc[i][j] = (f32x4){0.f,0.f,0.f,0.f};
    kloop_lds<4>(sH, Wo, wr*64, wc*64, lr, lk, acc);
    #pragma unroll
    for(int fm = 0; fm < 4; fm++)
      #pragma unroll
      for(int fn = 0; fn < 4; fn++)
        #pragma unroll
        for(int r = 0; r < 4; r++){
          int row = wr*64 + fm*16 + lk*4 + r;
          int col = wc*64 + fn*16 + lr;
          hW[(size_t)(row0 + row)*128 + col] = acc[fm][fn][r];
        }
  }
}

// ================= triplet segsum (sorted streams) =================
__global__ __launch_bounds__(256) void tsum_kernel(const int* __restrict__ offs, const int* __restrict__ kj_s,
                                                   const bf16* __restrict__ cbf_s, const bf16* __restrict__ x,
                                                   const float* __restrict__ Wc, bf16* __restrict__ ts){
  int e = blockIdx.x*4 + (threadIdx.x >> 6);
  int lane = threadIdx.x & 63;
  float wcv[16];
  #pragma unroll
  for(int s = 0; s < 16; s++) wcv[s] = Wc[s*64 + lane];
  float acc = 0.f;
  int b0 = offs[e], b1 = offs[e+1];
  for(int idx = b0; idx < b1; ++idx){
    int k = kj_s[idx];
    bf16x8 c0 = *(const bf16x8*)&cbf_s[(size_t)idx*16];
    bf16x8 c1 = *(const bf16x8*)&cbf_s[(size_t)idx*16 + 8];
    float cw = 0.f;
    #pragma unroll
    for(int j = 0; j < 8; j++) cw += bfx(c0,j)*wcv[j] + bfx(c1,j)*wcv[8+j];
    acc += bf2f(x[(size_t)k*64 + lane]) * cw;
  }
  ts[(size_t)e*64 + lane] = f2bf(acc);
}

// ================= edge->atom segsum =================
__global__ __launch_bounds__(256) void asum_kernel(const int* __restrict__ offs, const int* __restrict__ list,
                                                   const bf16* __restrict__ buf, bf16* __restrict__ a){
  int g = blockIdx.x*256 + threadIdx.x;
  int i = g >> 4, c8 = g & 15;
  float acc[8];
  #pragma unroll
  for(int j = 0; j < 8; j++) acc[j] = 0.f;
  int b0 = offs[i], b1 = offs[i+1];
  for(int idx = b0; idx < b1; ++idx){
    bf16x8 v = *(const bf16x8*)&buf[(size_t)list[idx]*128 + c8*8];
    #pragma unroll
    for(int j = 0; j < 8; j++) acc[j] += bfx(v,j);
  }
  bf16x8 o;
  #pragma unroll
  for(int j = 0; j < 8; j++) o[j] = (__bf16)acc[j];
  *(bf16x8*)&a[(size_t)i*128 + c8*8] = o;
}

// ================= fused readout MLP (zred + 3 layers) =================
__global__ __launch_bounds__(256) void mlp_kernel(const float* __restrict__ hW, const int* __restrict__ numat,
    const float* __restrict__ W0, const float* __restrict__ b0,
    const float* __restrict__ W1, const float* __restrict__ b1,
    const float* __restrict__ W2, const float* __restrict__ b2,
    float* __restrict__ out)
{
  __shared__ float zs[128], x0[256], x1[256];
  int b = blockIdx.x, t = threadIdx.x;
  if(t < 128){
    float s = 0.f;
    #pragma unroll 4
    for(int i = 0; i < 32; i++) s += hW[((size_t)(b*32 + i))*128 + t];
    zs[t] = s / (float)numat[b];
  }
  __syncthreads();
  {
    float acc = b0[t];
    for(int k = 0; k < 128; k++) acc += zs[k] * W0[(size_t)k*256 + t];
    x0[t] = fmaxf(acc, 0.f);
  }
  __syncthreads();
  {
    float acc = b1[t];
    for(int k = 0; k < 256; k++) acc += x0[k] * W1[(size_t)k*256 + t];
    x1[t] = fmaxf(acc, 0.f);
  }
  __syncthreads();
  if(t < 230){
    float acc = b2[t];
    for(int k = 0; k < 256; k++) acc += x1[k] * W2[(size_t)k*230 + t];
    out[(size_t)b*230 + t] = acc;
  }
}

extern "C" void kernel_launch(void* const* d_in, const int* in_sizes, int n_in,
                              void* d_out, int out_size, void* d_ws, size_t ws_size,
                              hipStream_t stream)
{
  const float* noise   = (const float*)d_in[0];
  const float* frac    = (const float*)d_in[1];
  const float* lengths = (const float*)d_in[2];
  const float* angles  = (const float*)d_in[3];
  const int*   types   = (const int*)d_in[4];
  const int*   numat   = (const int*)d_in[5];
  const int*   ei      = (const int*)d_in[6];
  const int*   ji      = (const int*)d_in[7];
  const int*   kj      = (const int*)d_in[8];
  const float* emb     = (const float*)d_in[9];
  const float* Whz     = (const float*)d_in[10];
  const float* Wedge   = (const float*)d_in[11];
  const float* Wm      = (const float*)d_in[12];
  const float* Wr1     = (const float*)d_in[13];
  const float* Wdown   = (const float*)d_in[14];
  const float* Wcbf    = (const float*)d_in[15];
  const float* Wup     = (const float*)d_in[16];
  const float* Wa      = (const float*)d_in[17];
  const float* Wr2     = (const float*)d_in[18];
  const float* Wh      = (const float*)d_in[19];
  const float* Wsw     = (const float*)d_in[20];
  const float* Wtw     = (const float*)d_in[21];
  const float* Wout    = (const float*)d_in[22];
  const float* Wfc0    = (const float*)d_in[23];
  const float* bfc0    = (const float*)d_in[24];
  const float* Wfc1    = (const float*)d_in[25];
  const float* bfc1    = (const float*)d_in[26];
  const float* Wfc2    = (const float*)d_in[27];
  const float* bfc2    = (const float*)d_in[28];
  float* out = (float*)d_out;

  char* base = (char*)d_ws;
  size_t oo = 0;
  auto ab = [&](size_t bytes)->void*{ void* p = base + oo; oo += bytes; oo = (oo + 63) & ~(size_t)63; return p; };

  float* pos   = (float*)ab((size_t)N_*3*4);
  float* vec   = (float*)ab((size_t)E_*3*4);
  bf16*  rbf   = (bf16*) ab((size_t)E_*64*2);
  bf16*  cbf_s = (bf16*) ab((size_t)T_*16*2);
  int*   kj_s  = (int*)  ab((size_t)T_*4);
  float* h     = (float*)ab((size_t)N_*128*4);
  bf16*  hbf   = (bf16*) ab((size_t)N_*128*2);
  bf16*  m     = (bf16*) ab((size_t)E_*128*2);
  bf16*  tmp   = (bf16*) ab((size_t)E_*128*2);
  bf16*  ts    = (bf16*) ab((size_t)E_*64*2);
  bf16*  xbuf  = (bf16*) ab((size_t)E_*64*2);
  bf16*  a     = (bf16*) ab((size_t)N_*128*2);
  bf16*  hsb   = (bf16*) ab((size_t)N_*128*2);
  bf16*  htb   = (bf16*) ab((size_t)N_*128*2);
  float* hW    = (float*)ab((size_t)N_*128*4);

  bf16* WedgeT = (bf16*)ab(320*128*2);
  bf16* WmT    = (bf16*)ab((size_t)3*128*128*2);
  bf16* Wr1T   = (bf16*)ab((size_t)3*128*64*2);
  bf16* WdownT = (bf16*)ab((size_t)3*64*128*2);
  bf16* WupT   = (bf16*)ab((size_t)3*128*64*2);
  bf16* WaT    = (bf16*)ab((size_t)3*128*128*2);
  bf16* Wr2T   = (bf16*)ab((size_t)3*128*64*2);
  bf16* WhT    = (bf16*)ab((size_t)3*128*128*2);
  bf16* WstT   = (bf16*)ab((size_t)3*2*128*128*2);
  bf16* WoutT  = (bf16*)ab(128*128*2);

  int* cnt_ji   = (int*)ab((size_t)(E_ + N_)*4);   // cnt_ji || cnt_dst adjacent (single memset)
  int* cnt_dst  = cnt_ji + E_;
  int* off_ji   = (int*)ab((size_t)(E_+1)*4);
  int* cur_ji   = (int*)ab((size_t)E_*4);
  int* list_ji  = (int*)ab((size_t)T_*4);
  int* off_dst  = (int*)ab((size_t)(N_+1)*4);
  int* cur_dst  = (int*)ab((size_t)N_*4);
  int* list_dst = (int*)ab((size_t)E_*4);
  int* bsum     = (int*)ab(68*4);
  int* boff     = (int*)ab(68*4);

  // ---- weight conversion (single dispatch) ----
  WPackAll p{};
  {
    int i = 0;
    p.d[i++] = {Wedge, WedgeT, 320, 7};
    for(int b=0;b<3;b++) p.d[i++] = {Wm   + (size_t)b*128*128, WmT   + (size_t)b*128*128, 128, 7};
    for(int b=0;b<3;b++) p.d[i++] = {Wr1  + (size_t)b*64*128,  Wr1T  + (size_t)b*128*64,   64, 7};
    for(int b=0;b<3;b++) p.d[i++] = {Wdown+ (size_t)b*128*64,  WdownT+ (size_t)b*64*128,  128, 6};
    for(int b=0;b<3;b++) p.d[i++] = {Wup  + (size_t)b*64*128,  WupT  + (size_t)b*128*64,   64, 7};
    for(int b=0;b<3;b++) p.d[i++] = {Wa   + (size_t)b*128*128, WaT   + (size_t)b*128*128, 128, 7};
    for(int b=0;b<3;b++) p.d[i++] = {Wr2  + (size_t)b*64*128,  Wr2T  + (size_t)b*128*64,   64, 7};
    for(int b=0;b<3;b++) p.d[i++] = {Wh   + (size_t)b*128*128, WhT   + (size_t)b*128*128, 128, 7};
    for(int b=0;b<3;b++) p.d[i++] = {Wsw  + (size_t)b*128*128, WstT  + (size_t)b*2*128*128,            128, 7};
    for(int b=0;b<3;b++) p.d[i++] = {Wtw  + (size_t)b*128*128, WstT  + (size_t)b*2*128*128 + 128*128,  128, 7};
    p.d[i++] = {Wout, WoutT, 128, 7};
    wconv_kernel<<<dim3(160,29), 256, 0, stream>>>(p);
  }

  // ---- CSR builds (hierarchical scan: all phases wide + coalesced) ----
  hipMemsetAsync(cnt_ji, 0, (size_t)(E_ + N_)*sizeof(int), stream);
  hist2_kernel<<<(T_+E_)/256, 256, 0, stream>>>(ji, ei + E_, cnt_ji, cnt_dst);
  scanA_kernel<<<68, 256, 0, stream>>>(cnt_ji, cnt_dst, bsum);
  scanB_kernel<<<1, 128, 0, stream>>>(bsum, boff);
  scanC_kernel<<<68, 256, 0, stream>>>(cnt_ji, cnt_dst, boff, off_ji, cur_ji, off_dst, cur_dst);
  fill2_kernel<<<(T_+E_)/256, 256, 0, stream>>>(ji, ei + E_, cur_ji, list_ji, cur_dst, list_dst);

  // ---- geometry + init ----
  pos_kernel<<<N_/256, 256, 0, stream>>>(frac, lengths, angles, pos);
  edge_kernel<<<E_/4, 256, 0, stream>>>(pos, ei, vec, rbf);
  tprep_kernel<<<T_/256, 256, 0, stream>>>(list_ji, ji, kj, vec, cbf_s, kj_s);
  h0_kernel<<<N_, 128, 0, stream>>>(emb, types, noise, Whz, h, hbf);
  mgemm_m0<<<E_/128, 256, 0, stream>>>(hbf, rbf, ei, WedgeT, m);

  for(int b = 0; b < 3; b++){
    const bf16* WmT_b  = WmT   + (size_t)b*128*128;
    const bf16* Wr1T_b = Wr1T  + (size_t)b*128*64;
    const bf16* WdT_b  = WdownT+ (size_t)b*64*128;
    const float* Wc_b  = Wcbf  + (size_t)b*16*64;
    const bf16* WuT_b  = WupT  + (size_t)b*128*64;
    const bf16* WaT_b  = WaT   + (size_t)b*128*128;
    const bf16* Wr2T_b = Wr2T  + (size_t)b*128*64;
    const bf16* WhT_b  = WhT   + (size_t)b*128*128;
    const bf16* WstT_b = WstT  + (size_t)b*2*128*128;

    // [scat of prev iter] + x = (silu(m@Wm)*(rbf@Wr1)) @ Wdown
    if(b == 0) dd_fused<false><<<E_/128, 256, 0, stream>>>(m, WmT_b, rbf, Wr1T_b, WdT_b, xbuf, ei, hsb, htb);
    else       dd_fused<true ><<<E_/128, 256, 0, stream>>>(m, WmT_b, rbf, Wr1T_b, WdT_b, xbuf, ei, hsb, htb);
    // ts = seg(x[kj] * (cbf@Wcbf), ji)
    tsum_kernel<<<E_/4, 256, 0, stream>>>(off_ji, kj_s, cbf_s, xbuf, Wc_b, ts);
    // m += silu(ts@Wup); tmp = silu(m@Wa)*(rbf@Wr2)
    if(b < 2) wup_wa<true ><<<E_/128, 256, 0, stream>>>(ts, WuT_b, m, WaT_b, rbf, Wr2T_b, tmp);
    else      wup_wa<false><<<E_/128, 256, 0, stream>>>(ts, WuT_b, m, WaT_b, rbf, Wr2T_b, tmp);
    // a = seg(tmp, dst)
    asum_kernel<<<N_*16/256, 256, 0, stream>>>(off_dst, list_dst, tmp, a);
    // h += silu(a@Wh); hs/ht (or hW on last iter)
    if(b < 2) atom_fused<false><<<N_/128, 256, 0, stream>>>(a, WhT_b, h, WstT_b, hsb, htb, WoutT, hW);
    else      atom_fused<true ><<<N_/128, 256, 0, stream>>>(a, WhT_b, h, WstT_b, hsb, htb, WoutT, hW);
  }

  // ---- fused readout ----
  mlp_kernel<<<B_, 256, 0, stream>>>(hW, numat, Wfc0, bfc0, Wfc1, bfc1, Wfc2, bfc2, out);
}